// Round 1
// baseline (472.881 us; speedup 1.0000x reference)
//
#include <hip/hip_runtime.h>
#include <hip/hip_bf16.h>
#include <cstddef>

#define NN 50000
#define EE 1600000
#define GG 512
#define NB 196        // ceil(NN/256) buckets of 256 nodes
#define BSTRIDE 16384 // fixed pairs-region capacity per bucket (max span ~8600)
#define BCAP 10240    // LDS staging per bucket
#define XBLKS 6250    // NN*32/256 x-convert blocks
#define SCBLKS 782    // ceil(EE/2048) bscatter blocks

typedef unsigned int u32;
typedef unsigned short u16;
typedef __attribute__((ext_vector_type(8))) short frag_ab;   // 8 bf16 = 4 VGPRs
typedef __attribute__((ext_vector_type(4))) float frag_cd;   // 4 fp32 acc

__device__ __forceinline__ void gl_lds16(const void* g, void* l) {
    __builtin_amdgcn_global_load_lds(
        (const __attribute__((address_space(1))) u32*)g,
        (__attribute__((address_space(3))) u32*)l, 16, 0, 0);
}
__device__ __forceinline__ float b2f_lo(u32 v) { return __uint_as_float(v << 16); }
__device__ __forceinline__ float b2f_hi(u32 v) { return __uint_as_float(v & 0xffff0000u); }
__device__ __forceinline__ float b2f(u32 v, int odd) { return odd ? b2f_hi(v) : b2f_lo(v); }
__device__ __forceinline__ u16 f2b(float x) {
    __hip_bfloat16 h = __float2bfloat16(x);
    return *(u16*)&h;
}
__device__ __forceinline__ u32 pack2(float lo, float hi) {
    return ((u32)f2b(hi) << 16) | f2b(lo);
}
__device__ __forceinline__ void acc2(float2& a, u32 v) {
    a.x += b2f_lo(v);
    a.y += b2f_hi(v);
}

// Gathered tensors are stored SLICE-MAJOR: [4 slices][N][32 ch] bf16 (64 B per
// node per slice). A single 32-ch slice is 3.2 MB < 4 MB per-XCD L2, so each
// gather pass has an L2-resident working set: fetch collapses to the 8-XCD
// compulsory fill (8 x 3.2 MB per pass) instead of thrash.

// ---------------- fused: edge bucket-scatter + x->bf16(slice-major) + weight prep ----

__global__ __launch_bounds__(256) void bscatter_prep_kernel(
    const int* __restrict__ ei, int* __restrict__ bcnt, u32* __restrict__ pairs,
    const float* __restrict__ x, u32* __restrict__ xslu,
    const float* __restrict__ Wr1, const float* __restrict__ Wo1,
    const float* __restrict__ Wr2, const float* __restrict__ Wo2,
    const float* __restrict__ Wr3, const float* __restrict__ Wo3,
    const float* __restrict__ br3,
    u16* __restrict__ BT1, u16* __restrict__ BT2, u16* __restrict__ BT3,
    float* __restrict__ bias3) {
    __shared__ int lcnt[NB];
    __shared__ int lbase[NB];
    __shared__ unsigned short lpos[2048];
    int bid = blockIdx.x, t = threadIdx.x;
    if (bid < SCBLKS) {
        int e0 = bid * 2048;
        u32 pk[8];   // packed (src<<8)|(dst&255) stashed across phases
        int bk[8];
        for (int i = t; i < NB; i += 256) lcnt[i] = 0;
        __syncthreads();
#pragma unroll
        for (int i = 0; i < 8; ++i) {
            int e = e0 + i * 256 + t;
            if (e < EE) {
                int dst = ei[EE + e], src = ei[e];
                int b = dst >> 8;
                bk[i] = b;
                pk[i] = ((u32)src << 8) | (u32)(dst & 255);
                lpos[i * 256 + t] = (unsigned short)atomicAdd(&lcnt[b], 1);
            } else bk[i] = -1;
        }
        __syncthreads();
        for (int i = t; i < NB; i += 256) lbase[i] = atomicAdd(&bcnt[i], lcnt[i]);
        __syncthreads();
#pragma unroll
        for (int i = 0; i < 8; ++i) {
            if (bk[i] >= 0) {
                int pos = lbase[bk[i]] + (int)lpos[i * 256 + t];
                pairs[(size_t)bk[i] * BSTRIDE + pos] = pk[i];
            }
        }
    } else if (bid < SCBLKS + XBLKS) {
        int idx = (bid - SCBLKS) * 256 + t;
        int row = idx >> 5, q = idx & 31;        // q: 4-channel group 0..31
        float4 v = *(const float4*)(x + (size_t)row * 128 + q * 4);
        int s = q >> 3;                           // slice 0..3 (32 ch each)
        u32* dst = xslu + (((size_t)(s * NN + row)) << 4) + ((q & 7) << 1);
        uint2 w;
        w.x = pack2(v.x, v.y);
        w.y = pack2(v.z, v.w);
        *(uint2*)dst = w;
    } else {
        int m = bid - SCBLKS - XBLKS;   // 0..255 output col
        int k = t;                       // reduction idx
        BT2[m * 256 + k] = f2b(k < 128 ? Wr2[k * 256 + m] : Wo2[(k - 128) * 256 + m]);
        BT3[m * 256 + k] = f2b(m < 128 ? Wr3[k * 128 + m] : Wo3[k * 128 + (m - 128)]);
        if (m < 128)
            BT1[m * 256 + k] = f2b(k < 128 ? Wr1[k * 128 + m] : Wo1[(k - 128) * 128 + m]);
        if (k == 0) bias3[m] = (m < 128) ? 0.f : br3[m - 128];
    }
}

// ---------------- CSR pass 2 (512 threads/block; srcl in u16) ----------------

__global__ __launch_bounds__(512) void bfill_kernel(const u32* __restrict__ pairs,
                                                    const int* __restrict__ bcnt,
                                                    int* __restrict__ ofs,
                                                    u16* __restrict__ srcl) {
    __shared__ int sc[256];
    __shared__ int cnts[256];
    __shared__ int lcnt[256];
    __shared__ int lcur[256];
    __shared__ int lbuf[BCAP];
    int b = blockIdx.x, t = threadIdx.x;
    if (t < 256) {
        int c = (t < NB) ? bcnt[t] : 0;
        cnts[t] = c;
        sc[t] = c;
        lcnt[t] = 0;
    }
    __syncthreads();
    for (int off = 1; off < 256; off <<= 1) {
        int v = (t >= off && t < 256) ? sc[t - off] : 0;
        __syncthreads();
        if (t < 256) sc[t] += v;
        __syncthreads();
    }
    int base = sc[b] - cnts[b];
    int span = cnts[b];
    const u32* pp = pairs + (size_t)b * BSTRIDE;
    for (int j = t; j < span; j += 512) atomicAdd(&lcnt[pp[j] & 255u], 1);
    __syncthreads();
    int nc = 0;
    if (t < 256) {
        nc = lcnt[t];
        sc[t] = nc;
    }
    __syncthreads();
    for (int off = 1; off < 256; off <<= 1) {
        int v = (t >= off && t < 256) ? sc[t - off] : 0;
        __syncthreads();
        if (t < 256) sc[t] += v;
        __syncthreads();
    }
    if (t < 256) {
        int excl = sc[t] - nc;
        int node = b * 256 + t;
        if (node < NN) ofs[node] = base + excl;
        lcur[t] = excl;
    }
    if (b == 0 && t == 256) ofs[NN] = EE;
    __syncthreads();
    for (int j = t; j < span; j += 512) {
        u32 p = pp[j];
        int pos = atomicAdd(&lcur[p & 255u], 1);
        int src = (int)(p >> 8);
        if (pos < BCAP) lbuf[pos] = src;
        else srcl[base + pos] = (u16)src;
    }
    __syncthreads();
    int lim = span < BCAP ? span : BCAP;
    for (int j = t; j < lim; j += 512) srcl[base + j] = (u16)lbuf[j];
}

// ---------------- slice-major bf16 pull: 4 passes (blockIdx.y), 32 ch each --------
// One wave per node per pass. q=lane>>2: 16 edge slots; l=lane&3: 8-ch group (16 B).
// Per-pass gather source is 3.2 MB -> L2-resident; fetch ~= compulsory 8-XCD fill.

__global__ __launch_bounds__(256) void pull_sl_kernel(const u32* __restrict__ Xsl,
                                                      const int* __restrict__ ofs,
                                                      const u16* __restrict__ srcl,
                                                      u32* __restrict__ aggu) {
    int node = blockIdx.x * 4 + (threadIdx.x >> 6);
    int p = blockIdx.y;
    int lane = threadIdx.x & 63;
    int q = lane >> 2, l = lane & 3;
    const u32* base = Xsl + ((size_t)p * NN << 4);
    int lo = ofs[node], hi = ofs[node + 1];
    float2 a0 = {0.f, 0.f}, a1 = {0.f, 0.f}, a2 = {0.f, 0.f}, a3 = {0.f, 0.f};
    int j = lo;
    for (; j + 31 < hi; j += 32) {
        int s0 = srcl[j + q], s1 = srcl[j + 16 + q];
        uint4 v0 = *(const uint4*)(base + ((size_t)s0 << 4) + l * 4);
        uint4 v1 = *(const uint4*)(base + ((size_t)s1 << 4) + l * 4);
        acc2(a0, v0.x); acc2(a1, v0.y); acc2(a2, v0.z); acc2(a3, v0.w);
        acc2(a0, v1.x); acc2(a1, v1.y); acc2(a2, v1.z); acc2(a3, v1.w);
    }
    for (; j + 15 < hi; j += 16) {
        int s = srcl[j + q];
        uint4 v = *(const uint4*)(base + ((size_t)s << 4) + l * 4);
        acc2(a0, v.x); acc2(a1, v.y); acc2(a2, v.z); acc2(a3, v.w);
    }
    if (j + q < hi) {
        int s = srcl[j + q];
        uint4 v = *(const uint4*)(base + ((size_t)s << 4) + l * 4);
        acc2(a0, v.x); acc2(a1, v.y); acc2(a2, v.z); acc2(a3, v.w);
    }
    float acc[8] = {a0.x, a0.y, a1.x, a1.y, a2.x, a2.y, a3.x, a3.y};
#pragma unroll
    for (int i = 0; i < 8; ++i) {
        acc[i] += __shfl_xor(acc[i], 4, 64);
        acc[i] += __shfl_xor(acc[i], 8, 64);
        acc[i] += __shfl_xor(acc[i], 16, 64);
        acc[i] += __shfl_xor(acc[i], 32, 64);
    }
    if (q == 0) {
        uint4 r;
        r.x = pack2(acc[0], acc[1]);
        r.y = pack2(acc[2], acc[3]);
        r.z = pack2(acc[4], acc[5]);
        r.w = pack2(acc[6], acc[7]);
        *(uint4*)(aggu + (size_t)node * 64 + p * 16 + l * 4) = r;
    }
}

// pull3: gather t3sl (slice-major) + add o3 (row-major [N][128]), h3 row-major out.
__global__ __launch_bounds__(256) void pull3_sl_kernel(const u32* __restrict__ Tsl,
                                                       const u32* __restrict__ o3u,
                                                       const int* __restrict__ ofs,
                                                       const u16* __restrict__ srcl,
                                                       u32* __restrict__ h3u) {
    int node = blockIdx.x * 4 + (threadIdx.x >> 6);
    int p = blockIdx.y;
    int lane = threadIdx.x & 63;
    int q = lane >> 2, l = lane & 3;
    const u32* base = Tsl + ((size_t)p * NN << 4);
    int lo = ofs[node], hi = ofs[node + 1];
    float2 a0 = {0.f, 0.f}, a1 = {0.f, 0.f}, a2 = {0.f, 0.f}, a3 = {0.f, 0.f};
    int j = lo;
    for (; j + 31 < hi; j += 32) {
        int s0 = srcl[j + q], s1 = srcl[j + 16 + q];
        uint4 v0 = *(const uint4*)(base + ((size_t)s0 << 4) + l * 4);
        uint4 v1 = *(const uint4*)(base + ((size_t)s1 << 4) + l * 4);
        acc2(a0, v0.x); acc2(a1, v0.y); acc2(a2, v0.z); acc2(a3, v0.w);
        acc2(a0, v1.x); acc2(a1, v1.y); acc2(a2, v1.z); acc2(a3, v1.w);
    }
    for (; j + 15 < hi; j += 16) {
        int s = srcl[j + q];
        uint4 v = *(const uint4*)(base + ((size_t)s << 4) + l * 4);
        acc2(a0, v.x); acc2(a1, v.y); acc2(a2, v.z); acc2(a3, v.w);
    }
    if (j + q < hi) {
        int s = srcl[j + q];
        uint4 v = *(const uint4*)(base + ((size_t)s << 4) + l * 4);
        acc2(a0, v.x); acc2(a1, v.y); acc2(a2, v.z); acc2(a3, v.w);
    }
    float acc[8] = {a0.x, a0.y, a1.x, a1.y, a2.x, a2.y, a3.x, a3.y};
#pragma unroll
    for (int i = 0; i < 8; ++i) {
        acc[i] += __shfl_xor(acc[i], 4, 64);
        acc[i] += __shfl_xor(acc[i], 8, 64);
        acc[i] += __shfl_xor(acc[i], 16, 64);
        acc[i] += __shfl_xor(acc[i], 32, 64);
    }
    if (q == 0) {
        uint4 o = *(const uint4*)(o3u + (size_t)node * 64 + p * 16 + l * 4);
        acc[0] += b2f_lo(o.x); acc[1] += b2f_hi(o.x);
        acc[2] += b2f_lo(o.y); acc[3] += b2f_hi(o.y);
        acc[4] += b2f_lo(o.z); acc[5] += b2f_hi(o.z);
        acc[6] += b2f_lo(o.w); acc[7] += b2f_hi(o.w);
        uint4 r;
        r.x = pack2(acc[0], acc[1]);
        r.y = pack2(acc[2], acc[3]);
        r.z = pack2(acc[4], acc[5]);
        r.w = pack2(acc[6], acc[7]);
        *(uint4*)(h3u + (size_t)node * 64 + p * 16 + l * 4) = r;
    }
}

// ---------------- bf16 MFMA GEMM: C = relu?(A @ BT^T + bias), K=256 ----------------
// amode 0: A = [A0 agg row-major N x128 | A1 slice-major 4 x N x 32]
// amode 1: A = A0 plain row-major N x 256
// cmode 0: C0 slice-major 128 cols (grid.x == 1)
// cmode 1: C0 row-major ldc=256
// cmode 2: cols 0-127 -> C0 slice-major, cols 128-255 -> C1 row-major N x 128

__global__ __launch_bounds__(256, 2) void gemm_bf_kernel(
    const u16* __restrict__ A0, const u16* __restrict__ A1,
    const u16* __restrict__ BT, const float* __restrict__ bias,
    u16* __restrict__ C0, u16* __restrict__ C1,
    int amode, int cmode, int relu) {
    __shared__ alignas(16) u16 As[128 * 32];
    __shared__ alignas(16) u16 Bs[128 * 32];
    const int t = threadIdx.x;
    const int lane = t & 63, wid = t >> 6;
    const int quad = lane >> 4, l16 = lane & 15;
    const int wm = wid >> 1, wn = wid & 1;
    const int row0 = blockIdx.y * 128, c0 = blockIdx.x * 128;

    frag_cd acc[4][4];
#pragma unroll
    for (int i = 0; i < 4; ++i)
#pragma unroll
        for (int j = 0; j < 4; ++j) acc[i][j] = (frag_cd)0.f;

    const int ca = t, cb = t + 256;
    const int ra = ca >> 2, oa = (ca & 3) * 8;
    const int rb = cb >> 2, ob = (cb & 3) * 8;
    const int garow = min(row0 + ra, NN - 1);
    const int gbrow = min(row0 + rb, NN - 1);

    for (int kk = 0; kk < 256; kk += 32) {
        const u16 *pa, *pb;
        if (amode) {
            pa = A0 + (size_t)garow * 256 + kk + oa;
            pb = A0 + (size_t)gbrow * 256 + kk + ob;
        } else if (kk < 128) {
            pa = A0 + (size_t)garow * 128 + kk + oa;
            pb = A0 + (size_t)gbrow * 128 + kk + ob;
        } else {
            int s = (kk >> 5) - 4;
            pa = A1 + (((size_t)(s * NN + garow)) << 5) + oa;
            pb = A1 + (((size_t)(s * NN + gbrow)) << 5) + ob;
        }
        __syncthreads();
        gl_lds16(pa, &As[ca * 8]);
        gl_lds16(pb, &As[cb * 8]);
        gl_lds16(BT + (size_t)(c0 + ra) * 256 + kk + oa, &Bs[ca * 8]);
        gl_lds16(BT + (size_t)(c0 + rb) * 256 + kk + ob, &Bs[cb * 8]);
        __syncthreads();

        frag_ab a[4], b[4];
#pragma unroll
        for (int mt = 0; mt < 4; ++mt)
            a[mt] = *(const frag_ab*)&As[(wm * 64 + mt * 16 + l16) * 32 + quad * 8];
#pragma unroll
        for (int nt = 0; nt < 4; ++nt)
            b[nt] = *(const frag_ab*)&Bs[(wn * 64 + nt * 16 + l16) * 32 + quad * 8];
#pragma unroll
        for (int mt = 0; mt < 4; ++mt)
#pragma unroll
            for (int nt = 0; nt < 4; ++nt)
                acc[mt][nt] = __builtin_amdgcn_mfma_f32_16x16x32_bf16(
                    a[mt], b[nt], acc[mt][nt], 0, 0, 0);
    }

#pragma unroll
    for (int nt = 0; nt < 4; ++nt) {
        int col128 = wn * 64 + nt * 16 + l16;
        int col = c0 + col128;
        float bv = bias[col];
#pragma unroll
        for (int mt = 0; mt < 4; ++mt) {
#pragma unroll
            for (int r = 0; r < 4; ++r) {
                int row = row0 + wm * 64 + mt * 16 + quad * 4 + r;
                if (row < NN) {
                    float v = acc[mt][nt][r] + bv;
                    if (relu) v = fmaxf(v, 0.f);
                    u16 hv = f2b(v);
                    if (cmode == 0) {
                        C0[(((size_t)((col128 >> 5) * NN + row)) << 5) + (col128 & 31)] = hv;
                    } else if (cmode == 1) {
                        C0[(size_t)row * 256 + col] = hv;
                    } else {
                        if (col < 128)
                            C0[(((size_t)((col >> 5) * NN + row)) << 5) + (col & 31)] = hv;
                        else
                            C1[(size_t)row * 128 + (col - 128)] = hv;
                    }
                }
            }
        }
    }
}

// ---------------- fused mean-pool + head (4 waves, unrolled scan) ----------------

__device__ inline int lower_bound_i(const int* a, int n, int v) {
    int lo = 0, hi = n;
    while (lo < hi) {
        int m = (lo + hi) >> 1;
        if (a[m] < v) lo = m + 1; else hi = m;
    }
    return lo;
}

__global__ __launch_bounds__(256) void pool_head_kernel(const u32* __restrict__ h3u,
                                                        const int* __restrict__ batch,
                                                        const float* __restrict__ W1,
                                                        const float* __restrict__ b1,
                                                        const float* __restrict__ W2,
                                                        const float* __restrict__ b2,
                                                        float* __restrict__ out) {
    __shared__ float ps[256];
    __shared__ float p[128];
    __shared__ float hid[40];
    int g = blockIdx.x, t = threadIdx.x;
    int c = t & 127, half = t >> 7;        // 2 row-groups x 128 channels
    int w = c >> 1, odd = c & 1;
    int lo = lower_bound_i(batch, NN, g);
    int hi = lower_bound_i(batch, NN, g + 1);
    float s = 0.f;
    int i = lo + half;
    for (; i + 6 < hi; i += 8) {           // 4 independent loads in flight
        u32 v0 = h3u[(size_t)i * 64 + w];
        u32 v1 = h3u[(size_t)(i + 2) * 64 + w];
        u32 v2 = h3u[(size_t)(i + 4) * 64 + w];
        u32 v3 = h3u[(size_t)(i + 6) * 64 + w];
        s += (b2f(v0, odd) + b2f(v1, odd)) + (b2f(v2, odd) + b2f(v3, odd));
    }
    for (; i < hi; i += 2) s += b2f(h3u[(size_t)i * 64 + w], odd);
    ps[t] = s;
    __syncthreads();
    if (half == 0) p[c] = (ps[c] + ps[c + 128]) / fmaxf((float)(hi - lo), 1.f);
    __syncthreads();
    if (t < 40) {
        float v = b1[t];
        for (int k = 0; k < 128; ++k) v += p[k] * W1[k * 40 + t];
        hid[t] = v;
    }
    __syncthreads();
    if (t < 10) {
        float v = b2[t];
        for (int j = 0; j < 40; ++j) v += hid[j] * W2[j * 10 + t];
        out[g * 10 + t] = v;
    }
}

// ---------------- launch ----------------

extern "C" void kernel_launch(void* const* d_in, const int* in_sizes, int n_in,
                              void* d_out, int out_size, void* d_ws, size_t ws_size,
                              hipStream_t stream) {
    const float* x   = (const float*)d_in[0];
    const int* ei    = (const int*)d_in[1];
    const int* batch = (const int*)d_in[2];
    const float* Wr1 = (const float*)d_in[3];
    const float* br1 = (const float*)d_in[4];
    const float* Wo1 = (const float*)d_in[5];
    const float* Wr2 = (const float*)d_in[6];
    const float* br2 = (const float*)d_in[7];
    const float* Wo2 = (const float*)d_in[8];
    const float* Wr3 = (const float*)d_in[9];
    const float* br3 = (const float*)d_in[10];
    const float* Wo3 = (const float*)d_in[11];
    const float* W1  = (const float*)d_in[12];
    const float* b1  = (const float*)d_in[13];
    const float* W2  = (const float*)d_in[14];
    const float* b2  = (const float*)d_in[15];
    float* out = (float*)d_out;

    char* ws = (char*)d_ws;
    size_t off = 0;
    auto alloc = [&](size_t bytes) {
        void* p = ws + off;
        off += (bytes + 255) & ~(size_t)255;
        return p;
    };
    int* ofs      = (int*)alloc((NN + 1) * sizeof(int));
    int* bcnt     = (int*)alloc(256 * sizeof(int));
    u16* srcl     = (u16*)alloc((size_t)EE * 2);
    u16* xsl      = (u16*)alloc((size_t)NN * 128 * 2);   // slice-major x bf16
    u16* agg1     = (u16*)alloc((size_t)NN * 128 * 2);   // row-major agg(x)
    u16* h1sl     = (u16*)alloc((size_t)NN * 128 * 2);   // slice-major h1
    u16* agg2     = (u16*)alloc((size_t)NN * 128 * 2);   // row-major agg(h1)
    u16* h2       = (u16*)alloc((size_t)NN * 256 * 2);   // row-major h2
    u16* t3sl     = (u16*)alloc((size_t)NN * 128 * 2);   // slice-major t3
    u16* o3       = (u16*)alloc((size_t)NN * 128 * 2);   // row-major o3
    u16* h3       = (u16*)alloc((size_t)NN * 128 * 2);   // row-major h3 bf16
    u16* BT1      = (u16*)alloc(128 * 256 * 2);
    u16* BT2      = (u16*)alloc(256 * 256 * 2);
    u16* BT3      = (u16*)alloc(256 * 256 * 2);
    float* bias3  = (float*)alloc(256 * sizeof(float));
    // pairs (12.85 MB) overlays h2 (25.6 MB): pairs lifetime ends at bfill,
    // h2 first written at gemm2.
    u32* pairs = (u32*)h2;

    hipMemsetAsync(bcnt, 0, 256 * sizeof(int), stream);

    // CSR pass 1 + x->bf16 slice-major + weight prep (fused, independent block ranges)
    bscatter_prep_kernel<<<SCBLKS + XBLKS + 256, 256, 0, stream>>>(
        ei, bcnt, pairs, x, (u32*)xsl, Wr1, Wo1, Wr2, Wo2, Wr3, Wo3, br3,
        BT1, BT2, BT3, bias3);
    // CSR pass 2
    bfill_kernel<<<NB, 512, 0, stream>>>(pairs, bcnt, ofs, srcl);

    // conv1: agg1 = segsum(x), h1sl = relu([agg1|x] @ BT1^T + br1)
    pull_sl_kernel<<<dim3(NN / 4, 4), 256, 0, stream>>>(
        (const u32*)xsl, ofs, srcl, (u32*)agg1);
    gemm_bf_kernel<<<dim3(1, 391), 256, 0, stream>>>(
        agg1, xsl, BT1, br1, h1sl, nullptr, 0, 0, 1);
    // conv2: agg2 = segsum(h1), h2 = relu([agg2|h1] @ BT2^T + br2)
    pull_sl_kernel<<<dim3(NN / 4, 4), 256, 0, stream>>>(
        (const u32*)h1sl, ofs, srcl, (u32*)agg2);
    gemm_bf_kernel<<<dim3(2, 391), 256, 0, stream>>>(
        agg2, h1sl, BT2, br2, h2, nullptr, 0, 1, 1);
    // conv3: [t3sl|o3] = h2 @ [Wr3|Wo3] (+ [0|br3])
    gemm_bf_kernel<<<dim3(2, 391), 256, 0, stream>>>(
        h2, nullptr, BT3, bias3, t3sl, o3, 1, 2, 0);
    // h3 = agg(t3) + o3  (bf16)
    pull3_sl_kernel<<<dim3(NN / 4, 4), 256, 0, stream>>>(
        (const u32*)t3sl, (const u32*)o3, ofs, srcl, (u32*)h3);

    // fused mean pool + head
    pool_head_kernel<<<GG, 256, 0, stream>>>((const u32*)h3, batch, W1, b1, W2, b2, out);
}

// Round 2
// 397.431 us; speedup vs baseline: 1.1898x; 1.1898x over previous
//
#include <hip/hip_runtime.h>
#include <hip/hip_bf16.h>
#include <cstddef>

#define NN 50000
#define EE 1600000
#define GG 512
#define NB 196        // ceil(NN/256) buckets of 256 nodes
#define BSTRIDE 16384 // fixed pairs-region capacity per bucket (max span ~8600)
#define BCAP 10240    // LDS staging per bucket
#define XBLKS 6250    // NN*32/256 x-convert blocks
#define SCBLKS 782    // ceil(EE/2048) bscatter blocks
#define PBLKS 3125    // NN/16 pull blocks per pass (16 nodes/block, 4 nodes/wave)

typedef unsigned int u32;
typedef unsigned short u16;
typedef __attribute__((ext_vector_type(8))) short frag_ab;   // 8 bf16 = 4 VGPRs
typedef __attribute__((ext_vector_type(4))) float frag_cd;   // 4 fp32 acc

__device__ __forceinline__ void gl_lds16(const void* g, void* l) {
    __builtin_amdgcn_global_load_lds(
        (const __attribute__((address_space(1))) u32*)g,
        (__attribute__((address_space(3))) u32*)l, 16, 0, 0);
}
__device__ __forceinline__ float b2f_lo(u32 v) { return __uint_as_float(v << 16); }
__device__ __forceinline__ float b2f_hi(u32 v) { return __uint_as_float(v & 0xffff0000u); }
__device__ __forceinline__ float b2f(u32 v, int odd) { return odd ? b2f_hi(v) : b2f_lo(v); }
__device__ __forceinline__ u16 f2b(float x) {
    __hip_bfloat16 h = __float2bfloat16(x);
    return *(u16*)&h;
}
__device__ __forceinline__ u32 pack2(float lo, float hi) {
    return ((u32)f2b(hi) << 16) | f2b(lo);
}
__device__ __forceinline__ void acc2(float2& a, u32 v) {
    a.x += b2f_lo(v);
    a.y += b2f_hi(v);
}

// Gathered tensors are stored SLICE-MAJOR: [4 slices][N][32 ch] bf16 (64 B per
// node per slice). A single 32-ch slice is 3.2 MB < 4 MB per-XCD L2, so each
// gather pass has an L2-resident working set (fetch 152->83 MB, proven R1).
// Wave structure: 4 nodes/wave (sub=lane>>4), 4 edge slots (q=(lane>>2)&3),
// l=lane&3 covers the 64 B row. 16-edge body = 4 loads in flight per lane,
// 50000 waves total -- the R0-proven latency-hiding shape.

// ---------------- fused: edge bucket-scatter + x->bf16(slice-major) + weight prep ----

__global__ __launch_bounds__(256) void bscatter_prep_kernel(
    const int* __restrict__ ei, int* __restrict__ bcnt, u32* __restrict__ pairs,
    const float* __restrict__ x, u32* __restrict__ xslu,
    const float* __restrict__ Wr1, const float* __restrict__ Wo1,
    const float* __restrict__ Wr2, const float* __restrict__ Wo2,
    const float* __restrict__ Wr3, const float* __restrict__ Wo3,
    const float* __restrict__ br3,
    u16* __restrict__ BT1, u16* __restrict__ BT2, u16* __restrict__ BT3,
    float* __restrict__ bias3) {
    __shared__ int lcnt[NB];
    __shared__ int lbase[NB];
    __shared__ unsigned short lpos[2048];
    int bid = blockIdx.x, t = threadIdx.x;
    if (bid < SCBLKS) {
        int e0 = bid * 2048;
        u32 pk[8];   // packed (src<<8)|(dst&255) stashed across phases
        int bk[8];
        for (int i = t; i < NB; i += 256) lcnt[i] = 0;
        __syncthreads();
#pragma unroll
        for (int i = 0; i < 8; ++i) {
            int e = e0 + i * 256 + t;
            if (e < EE) {
                int dst = ei[EE + e], src = ei[e];
                int b = dst >> 8;
                bk[i] = b;
                pk[i] = ((u32)src << 8) | (u32)(dst & 255);
                lpos[i * 256 + t] = (unsigned short)atomicAdd(&lcnt[b], 1);
            } else bk[i] = -1;
        }
        __syncthreads();
        for (int i = t; i < NB; i += 256) lbase[i] = atomicAdd(&bcnt[i], lcnt[i]);
        __syncthreads();
#pragma unroll
        for (int i = 0; i < 8; ++i) {
            if (bk[i] >= 0) {
                int pos = lbase[bk[i]] + (int)lpos[i * 256 + t];
                pairs[(size_t)bk[i] * BSTRIDE + pos] = pk[i];
            }
        }
    } else if (bid < SCBLKS + XBLKS) {
        int idx = (bid - SCBLKS) * 256 + t;
        int row = idx >> 5, q = idx & 31;        // q: 4-channel group 0..31
        float4 v = *(const float4*)(x + (size_t)row * 128 + q * 4);
        int s = q >> 3;                           // slice 0..3 (32 ch each)
        u32* dst = xslu + (((size_t)(s * NN + row)) << 4) + ((q & 7) << 1);
        uint2 w;
        w.x = pack2(v.x, v.y);
        w.y = pack2(v.z, v.w);
        *(uint2*)dst = w;
    } else {
        int m = bid - SCBLKS - XBLKS;   // 0..255 output col
        int k = t;                       // reduction idx
        BT2[m * 256 + k] = f2b(k < 128 ? Wr2[k * 256 + m] : Wo2[(k - 128) * 256 + m]);
        BT3[m * 256 + k] = f2b(m < 128 ? Wr3[k * 128 + m] : Wo3[k * 128 + (m - 128)]);
        if (m < 128)
            BT1[m * 256 + k] = f2b(k < 128 ? Wr1[k * 128 + m] : Wo1[(k - 128) * 128 + m]);
        if (k == 0) bias3[m] = (m < 128) ? 0.f : br3[m - 128];
    }
}

// ---------------- CSR pass 2 (512 threads/block; srcl in u16) ----------------

__global__ __launch_bounds__(512) void bfill_kernel(const u32* __restrict__ pairs,
                                                    const int* __restrict__ bcnt,
                                                    int* __restrict__ ofs,
                                                    u16* __restrict__ srcl) {
    __shared__ int sc[256];
    __shared__ int cnts[256];
    __shared__ int lcnt[256];
    __shared__ int lcur[256];
    __shared__ int lbuf[BCAP];
    int b = blockIdx.x, t = threadIdx.x;
    if (t < 256) {
        int c = (t < NB) ? bcnt[t] : 0;
        cnts[t] = c;
        sc[t] = c;
        lcnt[t] = 0;
    }
    __syncthreads();
    for (int off = 1; off < 256; off <<= 1) {
        int v = (t >= off && t < 256) ? sc[t - off] : 0;
        __syncthreads();
        if (t < 256) sc[t] += v;
        __syncthreads();
    }
    int base = sc[b] - cnts[b];
    int span = cnts[b];
    const u32* pp = pairs + (size_t)b * BSTRIDE;
    for (int j = t; j < span; j += 512) atomicAdd(&lcnt[pp[j] & 255u], 1);
    __syncthreads();
    int nc = 0;
    if (t < 256) {
        nc = lcnt[t];
        sc[t] = nc;
    }
    __syncthreads();
    for (int off = 1; off < 256; off <<= 1) {
        int v = (t >= off && t < 256) ? sc[t - off] : 0;
        __syncthreads();
        if (t < 256) sc[t] += v;
        __syncthreads();
    }
    if (t < 256) {
        int excl = sc[t] - nc;
        int node = b * 256 + t;
        if (node < NN) ofs[node] = base + excl;
        lcur[t] = excl;
    }
    if (b == 0 && t == 256) ofs[NN] = EE;
    __syncthreads();
    for (int j = t; j < span; j += 512) {
        u32 p = pp[j];
        int pos = atomicAdd(&lcur[p & 255u], 1);
        int src = (int)(p >> 8);
        if (pos < BCAP) lbuf[pos] = src;
        else srcl[base + pos] = (u16)src;
    }
    __syncthreads();
    int lim = span < BCAP ? span : BCAP;
    for (int j = t; j < lim; j += 512) srcl[base + j] = (u16)lbuf[j];
}

// ---------------- slice-major bf16 pull: 4 passes (blockIdx.y), 32 ch each --------
// 4 nodes per wave; q=(lane>>2)&3: edge slot; l=lane&3: 16B channel group.
// 16-edge unrolled body = 4 independent gather loads in flight per lane.

__global__ __launch_bounds__(256) void pull_sl_kernel(const u32* __restrict__ Xsl,
                                                      const int* __restrict__ ofs,
                                                      const u16* __restrict__ srcl,
                                                      u32* __restrict__ aggu) {
    int lane = threadIdx.x & 63;
    int sub = lane >> 4;
    int q = (lane >> 2) & 3, l = lane & 3;
    int node = blockIdx.x * 16 + (threadIdx.x >> 6) * 4 + sub;
    int p = blockIdx.y;
    const u32* base = Xsl + ((size_t)p * NN << 4);
    int lo = ofs[node], hi = ofs[node + 1];
    float2 a0 = {0.f, 0.f}, a1 = {0.f, 0.f}, a2 = {0.f, 0.f}, a3 = {0.f, 0.f};
    int j = lo;
    for (; j + 15 < hi; j += 16) {
        int s0 = srcl[j + q], s1 = srcl[j + 4 + q];
        int s2 = srcl[j + 8 + q], s3 = srcl[j + 12 + q];
        uint4 v0 = *(const uint4*)(base + ((size_t)s0 << 4) + l * 4);
        uint4 v1 = *(const uint4*)(base + ((size_t)s1 << 4) + l * 4);
        uint4 v2 = *(const uint4*)(base + ((size_t)s2 << 4) + l * 4);
        uint4 v3 = *(const uint4*)(base + ((size_t)s3 << 4) + l * 4);
        acc2(a0, v0.x); acc2(a1, v0.y); acc2(a2, v0.z); acc2(a3, v0.w);
        acc2(a0, v1.x); acc2(a1, v1.y); acc2(a2, v1.z); acc2(a3, v1.w);
        acc2(a0, v2.x); acc2(a1, v2.y); acc2(a2, v2.z); acc2(a3, v2.w);
        acc2(a0, v3.x); acc2(a1, v3.y); acc2(a2, v3.z); acc2(a3, v3.w);
    }
    for (; j + 3 < hi; j += 4) {
        int s = srcl[j + q];
        uint4 v = *(const uint4*)(base + ((size_t)s << 4) + l * 4);
        acc2(a0, v.x); acc2(a1, v.y); acc2(a2, v.z); acc2(a3, v.w);
    }
    if (j + q < hi) {
        int s = srcl[j + q];
        uint4 v = *(const uint4*)(base + ((size_t)s << 4) + l * 4);
        acc2(a0, v.x); acc2(a1, v.y); acc2(a2, v.z); acc2(a3, v.w);
    }
    float acc[8] = {a0.x, a0.y, a1.x, a1.y, a2.x, a2.y, a3.x, a3.y};
#pragma unroll
    for (int i = 0; i < 8; ++i) {
        acc[i] += __shfl_xor(acc[i], 4, 64);
        acc[i] += __shfl_xor(acc[i], 8, 64);
    }
    if (q == 0) {
        uint4 r;
        r.x = pack2(acc[0], acc[1]);
        r.y = pack2(acc[2], acc[3]);
        r.z = pack2(acc[4], acc[5]);
        r.w = pack2(acc[6], acc[7]);
        *(uint4*)(aggu + (size_t)node * 64 + p * 16 + l * 4) = r;
    }
}

// pull3: gather t3sl (slice-major) + add o3 (row-major [N][128]), h3 row-major out.
__global__ __launch_bounds__(256) void pull3_sl_kernel(const u32* __restrict__ Tsl,
                                                       const u32* __restrict__ o3u,
                                                       const int* __restrict__ ofs,
                                                       const u16* __restrict__ srcl,
                                                       u32* __restrict__ h3u) {
    int lane = threadIdx.x & 63;
    int sub = lane >> 4;
    int q = (lane >> 2) & 3, l = lane & 3;
    int node = blockIdx.x * 16 + (threadIdx.x >> 6) * 4 + sub;
    int p = blockIdx.y;
    const u32* base = Tsl + ((size_t)p * NN << 4);
    int lo = ofs[node], hi = ofs[node + 1];
    float2 a0 = {0.f, 0.f}, a1 = {0.f, 0.f}, a2 = {0.f, 0.f}, a3 = {0.f, 0.f};
    int j = lo;
    for (; j + 15 < hi; j += 16) {
        int s0 = srcl[j + q], s1 = srcl[j + 4 + q];
        int s2 = srcl[j + 8 + q], s3 = srcl[j + 12 + q];
        uint4 v0 = *(const uint4*)(base + ((size_t)s0 << 4) + l * 4);
        uint4 v1 = *(const uint4*)(base + ((size_t)s1 << 4) + l * 4);
        uint4 v2 = *(const uint4*)(base + ((size_t)s2 << 4) + l * 4);
        uint4 v3 = *(const uint4*)(base + ((size_t)s3 << 4) + l * 4);
        acc2(a0, v0.x); acc2(a1, v0.y); acc2(a2, v0.z); acc2(a3, v0.w);
        acc2(a0, v1.x); acc2(a1, v1.y); acc2(a2, v1.z); acc2(a3, v1.w);
        acc2(a0, v2.x); acc2(a1, v2.y); acc2(a2, v2.z); acc2(a3, v2.w);
        acc2(a0, v3.x); acc2(a1, v3.y); acc2(a2, v3.z); acc2(a3, v3.w);
    }
    for (; j + 3 < hi; j += 4) {
        int s = srcl[j + q];
        uint4 v = *(const uint4*)(base + ((size_t)s << 4) + l * 4);
        acc2(a0, v.x); acc2(a1, v.y); acc2(a2, v.z); acc2(a3, v.w);
    }
    if (j + q < hi) {
        int s = srcl[j + q];
        uint4 v = *(const uint4*)(base + ((size_t)s << 4) + l * 4);
        acc2(a0, v.x); acc2(a1, v.y); acc2(a2, v.z); acc2(a3, v.w);
    }
    float acc[8] = {a0.x, a0.y, a1.x, a1.y, a2.x, a2.y, a3.x, a3.y};
#pragma unroll
    for (int i = 0; i < 8; ++i) {
        acc[i] += __shfl_xor(acc[i], 4, 64);
        acc[i] += __shfl_xor(acc[i], 8, 64);
    }
    if (q == 0) {
        uint4 o = *(const uint4*)(o3u + (size_t)node * 64 + p * 16 + l * 4);
        acc[0] += b2f_lo(o.x); acc[1] += b2f_hi(o.x);
        acc[2] += b2f_lo(o.y); acc[3] += b2f_hi(o.y);
        acc[4] += b2f_lo(o.z); acc[5] += b2f_hi(o.z);
        acc[6] += b2f_lo(o.w); acc[7] += b2f_hi(o.w);
        uint4 r;
        r.x = pack2(acc[0], acc[1]);
        r.y = pack2(acc[2], acc[3]);
        r.z = pack2(acc[4], acc[5]);
        r.w = pack2(acc[6], acc[7]);
        *(uint4*)(h3u + (size_t)node * 64 + p * 16 + l * 4) = r;
    }
}

// ---------------- bf16 MFMA GEMM: C = relu?(A @ BT^T + bias), K=256 ----------------
// amode 0: A = [A0 agg row-major N x128 | A1 slice-major 4 x N x 32]
// amode 1: A = A0 plain row-major N x 256
// cmode 0: C0 slice-major 128 cols (grid.x == 1)
// cmode 1: C0 row-major ldc=256
// cmode 2: cols 0-127 -> C0 slice-major, cols 128-255 -> C1 row-major N x 128

__global__ __launch_bounds__(256, 2) void gemm_bf_kernel(
    const u16* __restrict__ A0, const u16* __restrict__ A1,
    const u16* __restrict__ BT, const float* __restrict__ bias,
    u16* __restrict__ C0, u16* __restrict__ C1,
    int amode, int cmode, int relu) {
    __shared__ alignas(16) u16 As[128 * 32];
    __shared__ alignas(16) u16 Bs[128 * 32];
    const int t = threadIdx.x;
    const int lane = t & 63, wid = t >> 6;
    const int quad = lane >> 4, l16 = lane & 15;
    const int wm = wid >> 1, wn = wid & 1;
    const int row0 = blockIdx.y * 128, c0 = blockIdx.x * 128;

    frag_cd acc[4][4];
#pragma unroll
    for (int i = 0; i < 4; ++i)
#pragma unroll
        for (int j = 0; j < 4; ++j) acc[i][j] = (frag_cd)0.f;

    const int ca = t, cb = t + 256;
    const int ra = ca >> 2, oa = (ca & 3) * 8;
    const int rb = cb >> 2, ob = (cb & 3) * 8;
    const int garow = min(row0 + ra, NN - 1);
    const int gbrow = min(row0 + rb, NN - 1);

    for (int kk = 0; kk < 256; kk += 32) {
        const u16 *pa, *pb;
        if (amode) {
            pa = A0 + (size_t)garow * 256 + kk + oa;
            pb = A0 + (size_t)gbrow * 256 + kk + ob;
        } else if (kk < 128) {
            pa = A0 + (size_t)garow * 128 + kk + oa;
            pb = A0 + (size_t)gbrow * 128 + kk + ob;
        } else {
            int s = (kk >> 5) - 4;
            pa = A1 + (((size_t)(s * NN + garow)) << 5) + oa;
            pb = A1 + (((size_t)(s * NN + gbrow)) << 5) + ob;
        }
        __syncthreads();
        gl_lds16(pa, &As[ca * 8]);
        gl_lds16(pb, &As[cb * 8]);
        gl_lds16(BT + (size_t)(c0 + ra) * 256 + kk + oa, &Bs[ca * 8]);
        gl_lds16(BT + (size_t)(c0 + rb) * 256 + kk + ob, &Bs[cb * 8]);
        __syncthreads();

        frag_ab a[4], b[4];
#pragma unroll
        for (int mt = 0; mt < 4; ++mt)
            a[mt] = *(const frag_ab*)&As[(wm * 64 + mt * 16 + l16) * 32 + quad * 8];
#pragma unroll
        for (int nt = 0; nt < 4; ++nt)
            b[nt] = *(const frag_ab*)&Bs[(wn * 64 + nt * 16 + l16) * 32 + quad * 8];
#pragma unroll
        for (int mt = 0; mt < 4; ++mt)
#pragma unroll
            for (int nt = 0; nt < 4; ++nt)
                acc[mt][nt] = __builtin_amdgcn_mfma_f32_16x16x32_bf16(
                    a[mt], b[nt], acc[mt][nt], 0, 0, 0);
    }

#pragma unroll
    for (int nt = 0; nt < 4; ++nt) {
        int col128 = wn * 64 + nt * 16 + l16;
        int col = c0 + col128;
        float bv = bias[col];
#pragma unroll
        for (int mt = 0; mt < 4; ++mt) {
#pragma unroll
            for (int r = 0; r < 4; ++r) {
                int row = row0 + wm * 64 + mt * 16 + quad * 4 + r;
                if (row < NN) {
                    float v = acc[mt][nt][r] + bv;
                    if (relu) v = fmaxf(v, 0.f);
                    u16 hv = f2b(v);
                    if (cmode == 0) {
                        C0[(((size_t)((col128 >> 5) * NN + row)) << 5) + (col128 & 31)] = hv;
                    } else if (cmode == 1) {
                        C0[(size_t)row * 256 + col] = hv;
                    } else {
                        if (col < 128)
                            C0[(((size_t)((col >> 5) * NN + row)) << 5) + (col & 31)] = hv;
                        else
                            C1[(size_t)row * 128 + (col - 128)] = hv;
                    }
                }
            }
        }
    }
}

// ---------------- fused mean-pool + head (4 waves, unrolled scan) ----------------

__device__ inline int lower_bound_i(const int* a, int n, int v) {
    int lo = 0, hi = n;
    while (lo < hi) {
        int m = (lo + hi) >> 1;
        if (a[m] < v) lo = m + 1; else hi = m;
    }
    return lo;
}

__global__ __launch_bounds__(256) void pool_head_kernel(const u32* __restrict__ h3u,
                                                        const int* __restrict__ batch,
                                                        const float* __restrict__ W1,
                                                        const float* __restrict__ b1,
                                                        const float* __restrict__ W2,
                                                        const float* __restrict__ b2,
                                                        float* __restrict__ out) {
    __shared__ float ps[256];
    __shared__ float p[128];
    __shared__ float hid[40];
    int g = blockIdx.x, t = threadIdx.x;
    int c = t & 127, half = t >> 7;        // 2 row-groups x 128 channels
    int w = c >> 1, odd = c & 1;
    int lo = lower_bound_i(batch, NN, g);
    int hi = lower_bound_i(batch, NN, g + 1);
    float s = 0.f;
    int i = lo + half;
    for (; i + 6 < hi; i += 8) {           // 4 independent loads in flight
        u32 v0 = h3u[(size_t)i * 64 + w];
        u32 v1 = h3u[(size_t)(i + 2) * 64 + w];
        u32 v2 = h3u[(size_t)(i + 4) * 64 + w];
        u32 v3 = h3u[(size_t)(i + 6) * 64 + w];
        s += (b2f(v0, odd) + b2f(v1, odd)) + (b2f(v2, odd) + b2f(v3, odd));
    }
    for (; i < hi; i += 2) s += b2f(h3u[(size_t)i * 64 + w], odd);
    ps[t] = s;
    __syncthreads();
    if (half == 0) p[c] = (ps[c] + ps[c + 128]) / fmaxf((float)(hi - lo), 1.f);
    __syncthreads();
    if (t < 40) {
        float v = b1[t];
        for (int k = 0; k < 128; ++k) v += p[k] * W1[k * 40 + t];
        hid[t] = v;
    }
    __syncthreads();
    if (t < 10) {
        float v = b2[t];
        for (int j = 0; j < 40; ++j) v += hid[j] * W2[j * 10 + t];
        out[g * 10 + t] = v;
    }
}

// ---------------- launch ----------------

extern "C" void kernel_launch(void* const* d_in, const int* in_sizes, int n_in,
                              void* d_out, int out_size, void* d_ws, size_t ws_size,
                              hipStream_t stream) {
    const float* x   = (const float*)d_in[0];
    const int* ei    = (const int*)d_in[1];
    const int* batch = (const int*)d_in[2];
    const float* Wr1 = (const float*)d_in[3];
    const float* br1 = (const float*)d_in[4];
    const float* Wo1 = (const float*)d_in[5];
    const float* Wr2 = (const float*)d_in[6];
    const float* br2 = (const float*)d_in[7];
    const float* Wo2 = (const float*)d_in[8];
    const float* Wr3 = (const float*)d_in[9];
    const float* br3 = (const float*)d_in[10];
    const float* Wo3 = (const float*)d_in[11];
    const float* W1  = (const float*)d_in[12];
    const float* b1  = (const float*)d_in[13];
    const float* W2  = (const float*)d_in[14];
    const float* b2  = (const float*)d_in[15];
    float* out = (float*)d_out;

    char* ws = (char*)d_ws;
    size_t off = 0;
    auto alloc = [&](size_t bytes) {
        void* p = ws + off;
        off += (bytes + 255) & ~(size_t)255;
        return p;
    };
    int* ofs      = (int*)alloc((NN + 1) * sizeof(int));
    int* bcnt     = (int*)alloc(256 * sizeof(int));
    u16* srcl     = (u16*)alloc((size_t)EE * 2);
    u16* xsl      = (u16*)alloc((size_t)NN * 128 * 2);   // slice-major x bf16
    u16* agg1     = (u16*)alloc((size_t)NN * 128 * 2);   // row-major agg(x)
    u16* h1sl     = (u16*)alloc((size_t)NN * 128 * 2);   // slice-major h1
    u16* agg2     = (u16*)alloc((size_t)NN * 128 * 2);   // row-major agg(h1)
    u16* h2       = (u16*)alloc((size_t)NN * 256 * 2);   // row-major h2
    u16* t3sl     = (u16*)alloc((size_t)NN * 128 * 2);   // slice-major t3
    u16* o3       = (u16*)alloc((size_t)NN * 128 * 2);   // row-major o3
    u16* h3       = (u16*)alloc((size_t)NN * 128 * 2);   // row-major h3 bf16
    u16* BT1      = (u16*)alloc(128 * 256 * 2);
    u16* BT2      = (u16*)alloc(256 * 256 * 2);
    u16* BT3      = (u16*)alloc(256 * 256 * 2);
    float* bias3  = (float*)alloc(256 * sizeof(float));
    // pairs (12.85 MB) overlays h2 (25.6 MB): pairs lifetime ends at bfill,
    // h2 first written at gemm2.
    u32* pairs = (u32*)h2;

    hipMemsetAsync(bcnt, 0, 256 * sizeof(int), stream);

    // CSR pass 1 + x->bf16 slice-major + weight prep (fused, independent block ranges)
    bscatter_prep_kernel<<<SCBLKS + XBLKS + 256, 256, 0, stream>>>(
        ei, bcnt, pairs, x, (u32*)xsl, Wr1, Wo1, Wr2, Wo2, Wr3, Wo3, br3,
        BT1, BT2, BT3, bias3);
    // CSR pass 2
    bfill_kernel<<<NB, 512, 0, stream>>>(pairs, bcnt, ofs, srcl);

    // conv1: agg1 = segsum(x), h1sl = relu([agg1|x] @ BT1^T + br1)
    pull_sl_kernel<<<dim3(PBLKS, 4), 256, 0, stream>>>(
        (const u32*)xsl, ofs, srcl, (u32*)agg1);
    gemm_bf_kernel<<<dim3(1, 391), 256, 0, stream>>>(
        agg1, xsl, BT1, br1, h1sl, nullptr, 0, 0, 1);
    // conv2: agg2 = segsum(h1), h2 = relu([agg2|h1] @ BT2^T + br2)
    pull_sl_kernel<<<dim3(PBLKS, 4), 256, 0, stream>>>(
        (const u32*)h1sl, ofs, srcl, (u32*)agg2);
    gemm_bf_kernel<<<dim3(2, 391), 256, 0, stream>>>(
        agg2, h1sl, BT2, br2, h2, nullptr, 0, 1, 1);
    // conv3: [t3sl|o3] = h2 @ [Wr3|Wo3] (+ [0|br3])
    gemm_bf_kernel<<<dim3(2, 391), 256, 0, stream>>>(
        h2, nullptr, BT3, bias3, t3sl, o3, 1, 2, 0);
    // h3 = agg(t3) + o3  (bf16)
    pull3_sl_kernel<<<dim3(PBLKS, 4), 256, 0, stream>>>(
        (const u32*)t3sl, (const u32*)o3, ofs, srcl, (u32*)h3);

    // fused mean pool + head
    pool_head_kernel<<<GG, 256, 0, stream>>>((const u32*)h3, batch, W1, b1, W2, b2, out);
}

// Round 3
// 352.471 us; speedup vs baseline: 1.3416x; 1.1276x over previous
//
#include <hip/hip_runtime.h>
#include <hip/hip_bf16.h>
#include <cstddef>

#define NN 50000
#define EE 1600000
#define GG 512
#define NB 196        // ceil(NN/256) buckets of 256 nodes
#define BSTRIDE 16384 // fixed pairs-region capacity per bucket (max span ~8600)
#define BCAP 10240    // LDS staging per bucket
#define XBLKS 6250    // NN*32/256 x-convert blocks
#define SCBLKS 782    // ceil(EE/2048) bscatter blocks

typedef unsigned int u32;
typedef unsigned short u16;
typedef __attribute__((ext_vector_type(8))) short frag_ab;   // 8 bf16 = 4 VGPRs
typedef __attribute__((ext_vector_type(4))) float frag_cd;   // 4 fp32 acc

__device__ __forceinline__ void gl_lds16(const void* g, void* l) {
    __builtin_amdgcn_global_load_lds(
        (const __attribute__((address_space(1))) u32*)g,
        (__attribute__((address_space(3))) u32*)l, 16, 0, 0);
}
__device__ __forceinline__ float b2f_lo(u32 v) { return __uint_as_float(v << 16); }
__device__ __forceinline__ float b2f_hi(u32 v) { return __uint_as_float(v & 0xffff0000u); }
__device__ __forceinline__ float b2f(u32 v, int odd) { return odd ? b2f_hi(v) : b2f_lo(v); }
__device__ __forceinline__ u16 f2b(float x) {
    __hip_bfloat16 h = __float2bfloat16(x);
    return *(u16*)&h;
}
__device__ __forceinline__ u32 pack2(float lo, float hi) {
    return ((u32)f2b(hi) << 16) | f2b(lo);
}
__device__ __forceinline__ void acc2(float2& a, u32 v) {
    a.x += b2f_lo(v);
    a.y += b2f_hi(v);
}

// Pull structure: R0-proven row-major gather (one wave/node, q=lane>>4 edge
// slot, l=lane&15 16B channel group, 16-edge unroll = 4 loads in flight).
// Measured invariant: ~49-53 us regardless of layout/fetch volume (R0 152MB
// @3.4TB/s == R2 95MB @1.9TB/s) -> pinned by logical gather segment
// throughput (6.4M x 64B), treated as floor. GEMM2+GEMM3 are fused instead.

// ---------------- fused: edge bucket-scatter + x->bf16 + weight prep ----------------

__global__ __launch_bounds__(256) void bscatter_prep_kernel(
    const int* __restrict__ ei, int* __restrict__ bcnt, u32* __restrict__ pairs,
    const float* __restrict__ x, u16* __restrict__ ax,
    const float* __restrict__ Wr1, const float* __restrict__ Wo1,
    const float* __restrict__ Wr2, const float* __restrict__ Wo2,
    const float* __restrict__ Wr3, const float* __restrict__ Wo3,
    const float* __restrict__ br3,
    u16* __restrict__ BT1, u16* __restrict__ BT2, u16* __restrict__ BT3,
    float* __restrict__ bias3) {
    __shared__ int lcnt[NB];
    __shared__ int lbase[NB];
    __shared__ unsigned short lpos[2048];
    int bid = blockIdx.x, t = threadIdx.x;
    if (bid < SCBLKS) {
        int e0 = bid * 2048;
        u32 pk[8];   // packed (src<<8)|(dst&255) stashed across phases
        int bk[8];
        for (int i = t; i < NB; i += 256) lcnt[i] = 0;
        __syncthreads();
#pragma unroll
        for (int i = 0; i < 8; ++i) {
            int e = e0 + i * 256 + t;
            if (e < EE) {
                int dst = ei[EE + e], src = ei[e];
                int b = dst >> 8;
                bk[i] = b;
                pk[i] = ((u32)src << 8) | (u32)(dst & 255);
                lpos[i * 256 + t] = (unsigned short)atomicAdd(&lcnt[b], 1);
            } else bk[i] = -1;
        }
        __syncthreads();
        for (int i = t; i < NB; i += 256) lbase[i] = atomicAdd(&bcnt[i], lcnt[i]);
        __syncthreads();
#pragma unroll
        for (int i = 0; i < 8; ++i) {
            if (bk[i] >= 0) {
                int pos = lbase[bk[i]] + (int)lpos[i * 256 + t];
                pairs[(size_t)bk[i] * BSTRIDE + pos] = pk[i];
            }
        }
    } else if (bid < SCBLKS + XBLKS) {
        int idx = (bid - SCBLKS) * 256 + t;
        int row = idx >> 5, q = idx & 31;
        float4 v = *(const float4*)(x + (size_t)row * 128 + q * 4);
        *(u32*)(ax + (size_t)row * 256 + 128 + q * 4) = pack2(v.x, v.y);
        *(u32*)(ax + (size_t)row * 256 + 128 + q * 4 + 2) = pack2(v.z, v.w);
    } else {
        int m = bid - SCBLKS - XBLKS;   // 0..255 output col
        int k = t;                       // reduction idx
        BT2[m * 256 + k] = f2b(k < 128 ? Wr2[k * 256 + m] : Wo2[(k - 128) * 256 + m]);
        BT3[m * 256 + k] = f2b(m < 128 ? Wr3[k * 128 + m] : Wo3[k * 128 + (m - 128)]);
        if (m < 128)
            BT1[m * 256 + k] = f2b(k < 128 ? Wr1[k * 128 + m] : Wo1[(k - 128) * 128 + m]);
        if (k == 0) bias3[m] = (m < 128) ? 0.f : br3[m - 128];
    }
}

// ---------------- CSR pass 2 (512 threads/block; srcl in u16) ----------------

__global__ __launch_bounds__(512) void bfill_kernel(const u32* __restrict__ pairs,
                                                    const int* __restrict__ bcnt,
                                                    int* __restrict__ ofs,
                                                    u16* __restrict__ srcl) {
    __shared__ int sc[256];
    __shared__ int cnts[256];
    __shared__ int lcnt[256];
    __shared__ int lcur[256];
    __shared__ int lbuf[BCAP];
    int b = blockIdx.x, t = threadIdx.x;
    if (t < 256) {
        int c = (t < NB) ? bcnt[t] : 0;
        cnts[t] = c;
        sc[t] = c;
        lcnt[t] = 0;
    }
    __syncthreads();
    for (int off = 1; off < 256; off <<= 1) {
        int v = (t >= off && t < 256) ? sc[t - off] : 0;
        __syncthreads();
        if (t < 256) sc[t] += v;
        __syncthreads();
    }
    int base = sc[b] - cnts[b];
    int span = cnts[b];
    const u32* pp = pairs + (size_t)b * BSTRIDE;
    for (int j = t; j < span; j += 512) atomicAdd(&lcnt[pp[j] & 255u], 1);
    __syncthreads();
    int nc = 0;
    if (t < 256) {
        nc = lcnt[t];
        sc[t] = nc;
    }
    __syncthreads();
    for (int off = 1; off < 256; off <<= 1) {
        int v = (t >= off && t < 256) ? sc[t - off] : 0;
        __syncthreads();
        if (t < 256) sc[t] += v;
        __syncthreads();
    }
    if (t < 256) {
        int excl = sc[t] - nc;
        int node = b * 256 + t;
        if (node < NN) ofs[node] = base + excl;
        lcur[t] = excl;
    }
    if (b == 0 && t == 256) ofs[NN] = EE;
    __syncthreads();
    for (int j = t; j < span; j += 512) {
        u32 p = pp[j];
        int pos = atomicAdd(&lcur[p & 255u], 1);
        int src = (int)(p >> 8);
        if (pos < BCAP) lbuf[pos] = src;
        else srcl[base + pos] = (u16)src;
    }
    __syncthreads();
    int lim = span < BCAP ? span : BCAP;
    for (int j = t; j < lim; j += 512) srcl[base + j] = (u16)lbuf[j];
}

// ---------------- bf16 pull, row-major, wide-load, 16-edge unroll (R0 proven) ----

__global__ __launch_bounds__(256) void pull_bf_kernel(const u32* __restrict__ Xu,
                                                      const int* __restrict__ ofs,
                                                      const u16* __restrict__ srcl,
                                                      u32* __restrict__ outu) {
    int node = (blockIdx.x * 256 + threadIdx.x) >> 6;
    int lane = threadIdx.x & 63;
    int q = lane >> 4, l = lane & 15;
    int lo = ofs[node], hi = ofs[node + 1];
    float2 a0 = {0.f, 0.f}, a1 = {0.f, 0.f}, a2 = {0.f, 0.f}, a3 = {0.f, 0.f};
    int j = lo;
    for (; j + 15 < hi; j += 16) {
        int s0 = srcl[j + q], s1 = srcl[j + 4 + q];
        int s2 = srcl[j + 8 + q], s3 = srcl[j + 12 + q];
        uint4 v0 = *(const uint4*)(Xu + (size_t)s0 * 128 + l * 4);
        uint4 v1 = *(const uint4*)(Xu + (size_t)s1 * 128 + l * 4);
        uint4 v2 = *(const uint4*)(Xu + (size_t)s2 * 128 + l * 4);
        uint4 v3 = *(const uint4*)(Xu + (size_t)s3 * 128 + l * 4);
        acc2(a0, v0.x); acc2(a1, v0.y); acc2(a2, v0.z); acc2(a3, v0.w);
        acc2(a0, v1.x); acc2(a1, v1.y); acc2(a2, v1.z); acc2(a3, v1.w);
        acc2(a0, v2.x); acc2(a1, v2.y); acc2(a2, v2.z); acc2(a3, v2.w);
        acc2(a0, v3.x); acc2(a1, v3.y); acc2(a2, v3.z); acc2(a3, v3.w);
    }
    for (; j + 3 < hi; j += 4) {
        int s = srcl[j + q];
        uint4 v = *(const uint4*)(Xu + (size_t)s * 128 + l * 4);
        acc2(a0, v.x); acc2(a1, v.y); acc2(a2, v.z); acc2(a3, v.w);
    }
    if (j + q < hi) {
        int s = srcl[j + q];
        uint4 v = *(const uint4*)(Xu + (size_t)s * 128 + l * 4);
        acc2(a0, v.x); acc2(a1, v.y); acc2(a2, v.z); acc2(a3, v.w);
    }
    float acc[8] = {a0.x, a0.y, a1.x, a1.y, a2.x, a2.y, a3.x, a3.y};
#pragma unroll
    for (int i = 0; i < 8; ++i) {
        acc[i] += __shfl_xor(acc[i], 16, 64);
        acc[i] += __shfl_xor(acc[i], 32, 64);
    }
    if (q == 0) {
        uint4 r;
        r.x = pack2(acc[0], acc[1]);
        r.y = pack2(acc[2], acc[3]);
        r.z = pack2(acc[4], acc[5]);
        r.w = pack2(acc[6], acc[7]);
        *(uint4*)(outu + (size_t)node * 128 + l * 4) = r;
    }
}

// pull3: gather t3 (cols 0..127) + add o3 (cols 128..255), bf16 h3 out (stride 64 u32).
__global__ __launch_bounds__(256) void pull3_kernel(const u32* __restrict__ Tu,
                                                    const int* __restrict__ ofs,
                                                    const u16* __restrict__ srcl,
                                                    u32* __restrict__ h3u) {
    int node = (blockIdx.x * 256 + threadIdx.x) >> 6;
    int lane = threadIdx.x & 63;
    int q = lane >> 4, l = lane & 15;
    int lo = ofs[node], hi = ofs[node + 1];
    float2 a0 = {0.f, 0.f}, a1 = {0.f, 0.f}, a2 = {0.f, 0.f}, a3 = {0.f, 0.f};
    int j = lo;
    for (; j + 15 < hi; j += 16) {
        int s0 = srcl[j + q], s1 = srcl[j + 4 + q];
        int s2 = srcl[j + 8 + q], s3 = srcl[j + 12 + q];
        uint4 v0 = *(const uint4*)(Tu + (size_t)s0 * 128 + l * 4);
        uint4 v1 = *(const uint4*)(Tu + (size_t)s1 * 128 + l * 4);
        uint4 v2 = *(const uint4*)(Tu + (size_t)s2 * 128 + l * 4);
        uint4 v3 = *(const uint4*)(Tu + (size_t)s3 * 128 + l * 4);
        acc2(a0, v0.x); acc2(a1, v0.y); acc2(a2, v0.z); acc2(a3, v0.w);
        acc2(a0, v1.x); acc2(a1, v1.y); acc2(a2, v1.z); acc2(a3, v1.w);
        acc2(a0, v2.x); acc2(a1, v2.y); acc2(a2, v2.z); acc2(a3, v2.w);
        acc2(a0, v3.x); acc2(a1, v3.y); acc2(a2, v3.z); acc2(a3, v3.w);
    }
    for (; j + 3 < hi; j += 4) {
        int s = srcl[j + q];
        uint4 v = *(const uint4*)(Tu + (size_t)s * 128 + l * 4);
        acc2(a0, v.x); acc2(a1, v.y); acc2(a2, v.z); acc2(a3, v.w);
    }
    if (j + q < hi) {
        int s = srcl[j + q];
        uint4 v = *(const uint4*)(Tu + (size_t)s * 128 + l * 4);
        acc2(a0, v.x); acc2(a1, v.y); acc2(a2, v.z); acc2(a3, v.w);
    }
    float acc[8] = {a0.x, a0.y, a1.x, a1.y, a2.x, a2.y, a3.x, a3.y};
#pragma unroll
    for (int i = 0; i < 8; ++i) {
        acc[i] += __shfl_xor(acc[i], 16, 64);
        acc[i] += __shfl_xor(acc[i], 32, 64);
    }
    if (q == 0) {
        uint4 o = *(const uint4*)(Tu + (size_t)node * 128 + 64 + l * 4);
        acc[0] += b2f_lo(o.x); acc[1] += b2f_hi(o.x);
        acc[2] += b2f_lo(o.y); acc[3] += b2f_hi(o.y);
        acc[4] += b2f_lo(o.z); acc[5] += b2f_hi(o.z);
        acc[6] += b2f_lo(o.w); acc[7] += b2f_hi(o.w);
        uint4 r;
        r.x = pack2(acc[0], acc[1]);
        r.y = pack2(acc[2], acc[3]);
        r.z = pack2(acc[4], acc[5]);
        r.w = pack2(acc[6], acc[7]);
        *(uint4*)(h3u + (size_t)node * 64 + l * 4) = r;
    }
}

// ---------------- bf16 MFMA GEMM: C = relu?(A @ BT^T + bias), K=256 ----------------

__global__ __launch_bounds__(256, 2) void gemm_bf_kernel(
    const u16* __restrict__ A, const u16* __restrict__ BT,
    const float* __restrict__ bias, u16* __restrict__ C,
    int ldc, int coloff, int relu) {
    __shared__ alignas(16) u16 As[128 * 32];
    __shared__ alignas(16) u16 Bs[128 * 32];
    const int t = threadIdx.x;
    const int lane = t & 63, wid = t >> 6;
    const int quad = lane >> 4, l16 = lane & 15;
    const int wm = wid >> 1, wn = wid & 1;
    const int row0 = blockIdx.y * 128, c0 = blockIdx.x * 128;

    frag_cd acc[4][4];
#pragma unroll
    for (int i = 0; i < 4; ++i)
#pragma unroll
        for (int j = 0; j < 4; ++j) acc[i][j] = (frag_cd)0.f;

    const int ca = t, cb = t + 256;
    const int ra = ca >> 2, oa = (ca & 3) * 8;
    const int rb = cb >> 2, ob = (cb & 3) * 8;
    const int garow = min(row0 + ra, NN - 1);
    const int gbrow = min(row0 + rb, NN - 1);
    const size_t gA1 = (size_t)garow * 256 + oa;
    const size_t gA2 = (size_t)gbrow * 256 + ob;
    const size_t gB1 = (size_t)(c0 + ra) * 256 + oa;
    const size_t gB2 = (size_t)(c0 + rb) * 256 + ob;

    for (int kk = 0; kk < 256; kk += 32) {
        __syncthreads();
        gl_lds16(A + gA1 + kk, &As[ca * 8]);
        gl_lds16(A + gA2 + kk, &As[cb * 8]);
        gl_lds16(BT + gB1 + kk, &Bs[ca * 8]);
        gl_lds16(BT + gB2 + kk, &Bs[cb * 8]);
        __syncthreads();

        frag_ab a[4], b[4];
#pragma unroll
        for (int mt = 0; mt < 4; ++mt)
            a[mt] = *(const frag_ab*)&As[(wm * 64 + mt * 16 + l16) * 32 + quad * 8];
#pragma unroll
        for (int nt = 0; nt < 4; ++nt)
            b[nt] = *(const frag_ab*)&Bs[(wn * 64 + nt * 16 + l16) * 32 + quad * 8];
#pragma unroll
        for (int mt = 0; mt < 4; ++mt)
#pragma unroll
            for (int nt = 0; nt < 4; ++nt)
                acc[mt][nt] = __builtin_amdgcn_mfma_f32_16x16x32_bf16(
                    a[mt], b[nt], acc[mt][nt], 0, 0, 0);
    }

#pragma unroll
    for (int nt = 0; nt < 4; ++nt) {
        int col = c0 + wn * 64 + nt * 16 + l16;
        float bv = bias[col];
#pragma unroll
        for (int mt = 0; mt < 4; ++mt) {
#pragma unroll
            for (int r = 0; r < 4; ++r) {
                int row = row0 + wm * 64 + mt * 16 + quad * 4 + r;
                if (row < NN) {
                    float v = acc[mt][nt][r] + bv;
                    if (relu) v = fmaxf(v, 0.f);
                    C[(size_t)row * ldc + coloff + col] = f2b(v);
                }
            }
        }
    }
}

// ---------------- fused GEMM2+GEMM3: t3o3 = (relu(A@BT2^T+br2)) @ BT3^T + bias3 ----
// Stage 1: full 128x256 h2 tile into XOR-swizzled LDS (bf16, same rounding as
// the unfused path). Stage 2: GEMM3 with A straight from LDS (no staging).
// Swizzle idx^=((row&7)<<3) breaks the 512B-stride 16-way bank conflict on the
// stage-2 ds_read_b128 (lanes l16 read 16 rows at one col) down to 2-way (free).
// LDS = 8+8+64 = 80 KB -> 2 blocks/CU.

__global__ __launch_bounds__(256, 2) void gemm23_kernel(
    const u16* __restrict__ A, const u16* __restrict__ BT2,
    const float* __restrict__ br2, const u16* __restrict__ BT3,
    const float* __restrict__ bias3, u16* __restrict__ C) {
    __shared__ alignas(16) u16 As[128 * 32];
    __shared__ alignas(16) u16 Bs[128 * 32];
    __shared__ alignas(16) u16 Hs[128 * 256];
    const int t = threadIdx.x;
    const int lane = t & 63, wid = t >> 6;
    const int quad = lane >> 4, l16 = lane & 15;
    const int wm = wid >> 1, wn = wid & 1;
    const int row0 = blockIdx.x * 128;

    const int ca = t, cb = t + 256;
    const int ra = ca >> 2, oa = (ca & 3) * 8;
    const int rb = cb >> 2, ob = (cb & 3) * 8;
    const int garow = min(row0 + ra, NN - 1);
    const int gbrow = min(row0 + rb, NN - 1);
    const size_t gA1 = (size_t)garow * 256 + oa;
    const size_t gA2 = (size_t)gbrow * 256 + ob;

    // ---- stage 1: h2 tile (both 128-col halves) ----
    for (int nb = 0; nb < 2; ++nb) {
        const int c0 = nb * 128;
        frag_cd acc[4][4];
#pragma unroll
        for (int i = 0; i < 4; ++i)
#pragma unroll
            for (int j = 0; j < 4; ++j) acc[i][j] = (frag_cd)0.f;

        for (int kk = 0; kk < 256; kk += 32) {
            __syncthreads();
            gl_lds16(A + gA1 + kk, &As[ca * 8]);
            gl_lds16(A + gA2 + kk, &As[cb * 8]);
            gl_lds16(BT2 + (size_t)(c0 + ra) * 256 + kk + oa, &Bs[ca * 8]);
            gl_lds16(BT2 + (size_t)(c0 + rb) * 256 + kk + ob, &Bs[cb * 8]);
            __syncthreads();

            frag_ab a[4], b[4];
#pragma unroll
            for (int mt = 0; mt < 4; ++mt)
                a[mt] = *(const frag_ab*)&As[(wm * 64 + mt * 16 + l16) * 32 + quad * 8];
#pragma unroll
            for (int nt = 0; nt < 4; ++nt)
                b[nt] = *(const frag_ab*)&Bs[(wn * 64 + nt * 16 + l16) * 32 + quad * 8];
#pragma unroll
            for (int mt = 0; mt < 4; ++mt)
#pragma unroll
                for (int nt = 0; nt < 4; ++nt)
                    acc[mt][nt] = __builtin_amdgcn_mfma_f32_16x16x32_bf16(
                        a[mt], b[nt], acc[mt][nt], 0, 0, 0);
        }
        // park h2 half-tile in LDS (bias + relu + bf16 round)
#pragma unroll
        for (int nt = 0; nt < 4; ++nt) {
            int col = c0 + wn * 64 + nt * 16 + l16;
            float bv = br2[col];
#pragma unroll
            for (int mt = 0; mt < 4; ++mt) {
#pragma unroll
                for (int r = 0; r < 4; ++r) {
                    int lr = wm * 64 + mt * 16 + quad * 4 + r;
                    float v = fmaxf(acc[mt][nt][r] + bv, 0.f);
                    Hs[(lr * 256 + col) ^ ((lr & 7) << 3)] = f2b(v);
                }
            }
        }
    }
    __syncthreads();

    // ---- stage 2: C = Hs @ BT3^T + bias3 (A from LDS, no staging) ----
    for (int nb = 0; nb < 2; ++nb) {
        const int c0 = nb * 128;
        frag_cd acc[4][4];
#pragma unroll
        for (int i = 0; i < 4; ++i)
#pragma unroll
            for (int j = 0; j < 4; ++j) acc[i][j] = (frag_cd)0.f;

        for (int kk = 0; kk < 256; kk += 32) {
            __syncthreads();
            gl_lds16(BT3 + (size_t)(c0 + ra) * 256 + kk + oa, &Bs[ca * 8]);
            gl_lds16(BT3 + (size_t)(c0 + rb) * 256 + kk + ob, &Bs[cb * 8]);
            __syncthreads();

            frag_ab a[4], b[4];
#pragma unroll
            for (int mt = 0; mt < 4; ++mt) {
                int lr = wm * 64 + mt * 16 + l16;
                a[mt] = *(const frag_ab*)&Hs[(lr * 256 + kk + quad * 8) ^ ((lr & 7) << 3)];
            }
#pragma unroll
            for (int nt = 0; nt < 4; ++nt)
                b[nt] = *(const frag_ab*)&Bs[(wn * 64 + nt * 16 + l16) * 32 + quad * 8];
#pragma unroll
            for (int mt = 0; mt < 4; ++mt)
#pragma unroll
                for (int nt = 0; nt < 4; ++nt)
                    acc[mt][nt] = __builtin_amdgcn_mfma_f32_16x16x32_bf16(
                        a[mt], b[nt], acc[mt][nt], 0, 0, 0);
        }
#pragma unroll
        for (int nt = 0; nt < 4; ++nt) {
            int col = c0 + wn * 64 + nt * 16 + l16;
            float bv = bias3[col];
#pragma unroll
            for (int mt = 0; mt < 4; ++mt) {
#pragma unroll
                for (int r = 0; r < 4; ++r) {
                    int row = row0 + wm * 64 + mt * 16 + quad * 4 + r;
                    if (row < NN) {
                        float v = acc[mt][nt][r] + bv;
                        C[(size_t)row * 256 + col] = f2b(v);
                    }
                }
            }
        }
    }
}

// ---------------- fused mean-pool + head (4 waves, unrolled scan) ----------------

__device__ inline int lower_bound_i(const int* a, int n, int v) {
    int lo = 0, hi = n;
    while (lo < hi) {
        int m = (lo + hi) >> 1;
        if (a[m] < v) lo = m + 1; else hi = m;
    }
    return lo;
}

__global__ __launch_bounds__(256) void pool_head_kernel(const u32* __restrict__ h3u,
                                                        const int* __restrict__ batch,
                                                        const float* __restrict__ W1,
                                                        const float* __restrict__ b1,
                                                        const float* __restrict__ W2,
                                                        const float* __restrict__ b2,
                                                        float* __restrict__ out) {
    __shared__ float ps[256];
    __shared__ float p[128];
    __shared__ float hid[40];
    int g = blockIdx.x, t = threadIdx.x;
    int c = t & 127, half = t >> 7;        // 2 row-groups x 128 channels
    int w = c >> 1, odd = c & 1;
    int lo = lower_bound_i(batch, NN, g);
    int hi = lower_bound_i(batch, NN, g + 1);
    float s = 0.f;
    int i = lo + half;
    for (; i + 6 < hi; i += 8) {           // 4 independent loads in flight
        u32 v0 = h3u[(size_t)i * 64 + w];
        u32 v1 = h3u[(size_t)(i + 2) * 64 + w];
        u32 v2 = h3u[(size_t)(i + 4) * 64 + w];
        u32 v3 = h3u[(size_t)(i + 6) * 64 + w];
        s += (b2f(v0, odd) + b2f(v1, odd)) + (b2f(v2, odd) + b2f(v3, odd));
    }
    for (; i < hi; i += 2) s += b2f(h3u[(size_t)i * 64 + w], odd);
    ps[t] = s;
    __syncthreads();
    if (half == 0) p[c] = (ps[c] + ps[c + 128]) / fmaxf((float)(hi - lo), 1.f);
    __syncthreads();
    if (t < 40) {
        float v = b1[t];
        for (int k = 0; k < 128; ++k) v += p[k] * W1[k * 40 + t];
        hid[t] = v;
    }
    __syncthreads();
    if (t < 10) {
        float v = b2[t];
        for (int j = 0; j < 40; ++j) v += hid[j] * W2[j * 10 + t];
        out[g * 10 + t] = v;
    }
}

// ---------------- launch ----------------

extern "C" void kernel_launch(void* const* d_in, const int* in_sizes, int n_in,
                              void* d_out, int out_size, void* d_ws, size_t ws_size,
                              hipStream_t stream) {
    const float* x   = (const float*)d_in[0];
    const int* ei    = (const int*)d_in[1];
    const int* batch = (const int*)d_in[2];
    const float* Wr1 = (const float*)d_in[3];
    const float* br1 = (const float*)d_in[4];
    const float* Wo1 = (const float*)d_in[5];
    const float* Wr2 = (const float*)d_in[6];
    const float* br2 = (const float*)d_in[7];
    const float* Wo2 = (const float*)d_in[8];
    const float* Wr3 = (const float*)d_in[9];
    const float* br3 = (const float*)d_in[10];
    const float* Wo3 = (const float*)d_in[11];
    const float* W1  = (const float*)d_in[12];
    const float* b1  = (const float*)d_in[13];
    const float* W2  = (const float*)d_in[14];
    const float* b2  = (const float*)d_in[15];
    float* out = (float*)d_out;

    char* ws = (char*)d_ws;
    size_t off = 0;
    auto alloc = [&](size_t bytes) {
        void* p = ws + off;
        off += (bytes + 255) & ~(size_t)255;
        return p;
    };
    int* ofs      = (int*)alloc((NN + 1) * sizeof(int));
    int* bcnt     = (int*)alloc(256 * sizeof(int));
    u16* srcl     = (u16*)alloc((size_t)EE * 2);
    u16* ax       = (u16*)alloc((size_t)NN * 256 * 2);   // cols 0-127 agg, 128-255 x_bf
    u16* ah1      = (u16*)alloc((size_t)NN * 256 * 2);   // cols 0-127 agg(h1), 128-255 h1
    u16* t3o3     = (u16*)alloc((size_t)NN * 256 * 2);   // cols 0-127 t3, 128-255 o3
    u16* h3       = (u16*)alloc((size_t)NN * 128 * 2);   // bf16
    u16* BT1      = (u16*)alloc(128 * 256 * 2);
    u16* BT2      = (u16*)alloc(256 * 256 * 2);
    u16* BT3      = (u16*)alloc(256 * 256 * 2);
    float* bias3  = (float*)alloc(256 * sizeof(float));
    // pairs (12.85 MB) overlays t3o3 (25.6 MB): pairs lifetime ends at bfill,
    // t3o3 first written at gemm23.
    u32* pairs = (u32*)t3o3;

    hipMemsetAsync(bcnt, 0, 256 * sizeof(int), stream);

    // CSR pass 1 + x->bf16 + weight prep (fused, independent block ranges)
    bscatter_prep_kernel<<<SCBLKS + XBLKS + 256, 256, 0, stream>>>(
        ei, bcnt, pairs, x, ax, Wr1, Wo1, Wr2, Wo2, Wr3, Wo3, br3,
        BT1, BT2, BT3, bias3);
    // CSR pass 2
    bfill_kernel<<<NB, 512, 0, stream>>>(pairs, bcnt, ofs, srcl);

    // conv1
    pull_bf_kernel<<<NN * 64 / 256, 256, 0, stream>>>((const u32*)ax + 64, ofs, srcl, (u32*)ax);
    gemm_bf_kernel<<<dim3(1, 391), 256, 0, stream>>>(ax, BT1, br1, ah1, 256, 128, 1);
    // conv2
    pull_bf_kernel<<<NN * 64 / 256, 256, 0, stream>>>((const u32*)ah1 + 64, ofs, srcl, (u32*)ah1);
    // conv2 GEMM + conv3 GEMM fused: t3o3 = relu(ah1@BT2^T+br2) @ BT3^T + bias3
    gemm23_kernel<<<391, 256, 0, stream>>>(ah1, BT2, br2, BT3, bias3, t3o3);
    // h3 = agg(t3) + o3  (bf16)
    pull3_kernel<<<NN * 64 / 256, 256, 0, stream>>>((const u32*)t3o3, ofs, srcl, (u32*)h3);

    // fused mean pool + head
    pool_head_kernel<<<GG, 256, 0, stream>>>((const u32*)h3, batch, W1, b1, W2, b2, out);
}

// Round 4
// 352.071 us; speedup vs baseline: 1.3431x; 1.0011x over previous
//
#include <hip/hip_runtime.h>
#include <hip/hip_bf16.h>
#include <cstddef>

#define NN 50000
#define EE 1600000
#define GG 512
#define NB 196        // ceil(NN/256) buckets of 256 nodes
#define BSTRIDE 16384 // fixed pairs-region capacity per bucket (max span ~8600)
#define BCAP 10240    // LDS staging per bucket
#define XBLKS 6250    // NN*32/256 x-convert blocks
#define SCBLKS 782    // ceil(EE/2048) bscatter blocks

typedef unsigned int u32;
typedef unsigned short u16;
typedef __attribute__((ext_vector_type(8))) short frag_ab;   // 8 bf16 = 4 VGPRs
typedef __attribute__((ext_vector_type(4))) float frag_cd;   // 4 fp32 acc

__device__ __forceinline__ void gl_lds16(const void* g, void* l) {
    __builtin_amdgcn_global_load_lds(
        (const __attribute__((address_space(1))) u32*)g,
        (__attribute__((address_space(3))) u32*)l, 16, 0, 0);
}
__device__ __forceinline__ float b2f_lo(u32 v) { return __uint_as_float(v << 16); }
__device__ __forceinline__ float b2f_hi(u32 v) { return __uint_as_float(v & 0xffff0000u); }
__device__ __forceinline__ float b2f(u32 v, int odd) { return odd ? b2f_hi(v) : b2f_lo(v); }
__device__ __forceinline__ u16 f2b(float x) {
    __hip_bfloat16 h = __float2bfloat16(x);
    return *(u16*)&h;
}
__device__ __forceinline__ u32 pack2(float lo, float hi) {
    return ((u32)f2b(hi) << 16) | f2b(lo);
}
__device__ __forceinline__ void acc2(float2& a, u32 v) {
    a.x += b2f_lo(v);
    a.y += b2f_hi(v);
}

// Pull structure: R0-proven row-major gather (one wave/node, q=lane>>4 edge
// slot, l=lane&15 16B channel group, 16-edge unroll = 4 loads in flight).
// Gather rate is latency/queue-bound: 2-deep MLP -> 5 TB/s, 4-deep -> 8.3 TB/s.
// pull3 is replaced by pool3: per-graph flat-range gather (graphs are
// contiguous dst ranges in the CSR) with an 8-deep shfl-fed pipeline, fused
// with mean-pool + head (h3 buffer and pool_head kernel eliminated).

// ---------------- fused: edge bucket-scatter + x->bf16 + weight prep ----------------

__global__ __launch_bounds__(256) void bscatter_prep_kernel(
    const int* __restrict__ ei, int* __restrict__ bcnt, u32* __restrict__ pairs,
    const float* __restrict__ x, u16* __restrict__ ax,
    const float* __restrict__ Wr1, const float* __restrict__ Wo1,
    const float* __restrict__ Wr2, const float* __restrict__ Wo2,
    const float* __restrict__ Wr3, const float* __restrict__ Wo3,
    const float* __restrict__ br3,
    u16* __restrict__ BT1, u16* __restrict__ BT2, u16* __restrict__ BT3,
    float* __restrict__ bias3) {
    __shared__ int lcnt[NB];
    __shared__ int lbase[NB];
    __shared__ unsigned short lpos[2048];
    int bid = blockIdx.x, t = threadIdx.x;
    if (bid < SCBLKS) {
        int e0 = bid * 2048;
        u32 pk[8];   // packed (src<<8)|(dst&255) stashed across phases
        int bk[8];
        for (int i = t; i < NB; i += 256) lcnt[i] = 0;
        __syncthreads();
#pragma unroll
        for (int i = 0; i < 8; ++i) {
            int e = e0 + i * 256 + t;
            if (e < EE) {
                int dst = ei[EE + e], src = ei[e];
                int b = dst >> 8;
                bk[i] = b;
                pk[i] = ((u32)src << 8) | (u32)(dst & 255);
                lpos[i * 256 + t] = (unsigned short)atomicAdd(&lcnt[b], 1);
            } else bk[i] = -1;
        }
        __syncthreads();
        for (int i = t; i < NB; i += 256) lbase[i] = atomicAdd(&bcnt[i], lcnt[i]);
        __syncthreads();
#pragma unroll
        for (int i = 0; i < 8; ++i) {
            if (bk[i] >= 0) {
                int pos = lbase[bk[i]] + (int)lpos[i * 256 + t];
                pairs[(size_t)bk[i] * BSTRIDE + pos] = pk[i];
            }
        }
    } else if (bid < SCBLKS + XBLKS) {
        int idx = (bid - SCBLKS) * 256 + t;
        int row = idx >> 5, q = idx & 31;
        float4 v = *(const float4*)(x + (size_t)row * 128 + q * 4);
        *(u32*)(ax + (size_t)row * 256 + 128 + q * 4) = pack2(v.x, v.y);
        *(u32*)(ax + (size_t)row * 256 + 128 + q * 4 + 2) = pack2(v.z, v.w);
    } else {
        int m = bid - SCBLKS - XBLKS;   // 0..255 output col
        int k = t;                       // reduction idx
        BT2[m * 256 + k] = f2b(k < 128 ? Wr2[k * 256 + m] : Wo2[(k - 128) * 256 + m]);
        BT3[m * 256 + k] = f2b(m < 128 ? Wr3[k * 128 + m] : Wo3[k * 128 + (m - 128)]);
        if (m < 128)
            BT1[m * 256 + k] = f2b(k < 128 ? Wr1[k * 128 + m] : Wo1[(k - 128) * 128 + m]);
        if (k == 0) bias3[m] = (m < 128) ? 0.f : br3[m - 128];
    }
}

// ---------------- CSR pass 2 (512 threads/block; srcl in u16) ----------------

__global__ __launch_bounds__(512) void bfill_kernel(const u32* __restrict__ pairs,
                                                    const int* __restrict__ bcnt,
                                                    int* __restrict__ ofs,
                                                    u16* __restrict__ srcl) {
    __shared__ int sc[256];
    __shared__ int cnts[256];
    __shared__ int lcnt[256];
    __shared__ int lcur[256];
    __shared__ int lbuf[BCAP];
    int b = blockIdx.x, t = threadIdx.x;
    if (t < 256) {
        int c = (t < NB) ? bcnt[t] : 0;
        cnts[t] = c;
        sc[t] = c;
        lcnt[t] = 0;
    }
    __syncthreads();
    for (int off = 1; off < 256; off <<= 1) {
        int v = (t >= off && t < 256) ? sc[t - off] : 0;
        __syncthreads();
        if (t < 256) sc[t] += v;
        __syncthreads();
    }
    int base = sc[b] - cnts[b];
    int span = cnts[b];
    const u32* pp = pairs + (size_t)b * BSTRIDE;
    for (int j = t; j < span; j += 512) atomicAdd(&lcnt[pp[j] & 255u], 1);
    __syncthreads();
    int nc = 0;
    if (t < 256) {
        nc = lcnt[t];
        sc[t] = nc;
    }
    __syncthreads();
    for (int off = 1; off < 256; off <<= 1) {
        int v = (t >= off && t < 256) ? sc[t - off] : 0;
        __syncthreads();
        if (t < 256) sc[t] += v;
        __syncthreads();
    }
    if (t < 256) {
        int excl = sc[t] - nc;
        int node = b * 256 + t;
        if (node < NN) ofs[node] = base + excl;
        lcur[t] = excl;
    }
    if (b == 0 && t == 256) ofs[NN] = EE;
    __syncthreads();
    for (int j = t; j < span; j += 512) {
        u32 p = pp[j];
        int pos = atomicAdd(&lcur[p & 255u], 1);
        int src = (int)(p >> 8);
        if (pos < BCAP) lbuf[pos] = src;
        else srcl[base + pos] = (u16)src;
    }
    __syncthreads();
    int lim = span < BCAP ? span : BCAP;
    for (int j = t; j < lim; j += 512) srcl[base + j] = (u16)lbuf[j];
}

// ---------------- bf16 pull, row-major, wide-load, 16-edge unroll (R0 proven) ----

__global__ __launch_bounds__(256) void pull_bf_kernel(const u32* __restrict__ Xu,
                                                      const int* __restrict__ ofs,
                                                      const u16* __restrict__ srcl,
                                                      u32* __restrict__ outu) {
    int node = (blockIdx.x * 256 + threadIdx.x) >> 6;
    int lane = threadIdx.x & 63;
    int q = lane >> 4, l = lane & 15;
    int lo = ofs[node], hi = ofs[node + 1];
    float2 a0 = {0.f, 0.f}, a1 = {0.f, 0.f}, a2 = {0.f, 0.f}, a3 = {0.f, 0.f};
    int j = lo;
    for (; j + 15 < hi; j += 16) {
        int s0 = srcl[j + q], s1 = srcl[j + 4 + q];
        int s2 = srcl[j + 8 + q], s3 = srcl[j + 12 + q];
        uint4 v0 = *(const uint4*)(Xu + (size_t)s0 * 128 + l * 4);
        uint4 v1 = *(const uint4*)(Xu + (size_t)s1 * 128 + l * 4);
        uint4 v2 = *(const uint4*)(Xu + (size_t)s2 * 128 + l * 4);
        uint4 v3 = *(const uint4*)(Xu + (size_t)s3 * 128 + l * 4);
        acc2(a0, v0.x); acc2(a1, v0.y); acc2(a2, v0.z); acc2(a3, v0.w);
        acc2(a0, v1.x); acc2(a1, v1.y); acc2(a2, v1.z); acc2(a3, v1.w);
        acc2(a0, v2.x); acc2(a1, v2.y); acc2(a2, v2.z); acc2(a3, v2.w);
        acc2(a0, v3.x); acc2(a1, v3.y); acc2(a2, v3.z); acc2(a3, v3.w);
    }
    for (; j + 3 < hi; j += 4) {
        int s = srcl[j + q];
        uint4 v = *(const uint4*)(Xu + (size_t)s * 128 + l * 4);
        acc2(a0, v.x); acc2(a1, v.y); acc2(a2, v.z); acc2(a3, v.w);
    }
    if (j + q < hi) {
        int s = srcl[j + q];
        uint4 v = *(const uint4*)(Xu + (size_t)s * 128 + l * 4);
        acc2(a0, v.x); acc2(a1, v.y); acc2(a2, v.z); acc2(a3, v.w);
    }
    float acc[8] = {a0.x, a0.y, a1.x, a1.y, a2.x, a2.y, a3.x, a3.y};
#pragma unroll
    for (int i = 0; i < 8; ++i) {
        acc[i] += __shfl_xor(acc[i], 16, 64);
        acc[i] += __shfl_xor(acc[i], 32, 64);
    }
    if (q == 0) {
        uint4 r;
        r.x = pack2(acc[0], acc[1]);
        r.y = pack2(acc[2], acc[3]);
        r.z = pack2(acc[4], acc[5]);
        r.w = pack2(acc[6], acc[7]);
        *(uint4*)(outu + (size_t)node * 128 + l * 4) = r;
    }
}

// ---------------- bf16 MFMA GEMM: C = relu?(A @ BT^T + bias), K=256 ----------------

__global__ __launch_bounds__(256, 2) void gemm_bf_kernel(
    const u16* __restrict__ A, const u16* __restrict__ BT,
    const float* __restrict__ bias, u16* __restrict__ C,
    int ldc, int coloff, int relu) {
    __shared__ alignas(16) u16 As[128 * 32];
    __shared__ alignas(16) u16 Bs[128 * 32];
    const int t = threadIdx.x;
    const int lane = t & 63, wid = t >> 6;
    const int quad = lane >> 4, l16 = lane & 15;
    const int wm = wid >> 1, wn = wid & 1;
    const int row0 = blockIdx.y * 128, c0 = blockIdx.x * 128;

    frag_cd acc[4][4];
#pragma unroll
    for (int i = 0; i < 4; ++i)
#pragma unroll
        for (int j = 0; j < 4; ++j) acc[i][j] = (frag_cd)0.f;

    const int ca = t, cb = t + 256;
    const int ra = ca >> 2, oa = (ca & 3) * 8;
    const int rb = cb >> 2, ob = (cb & 3) * 8;
    const int garow = min(row0 + ra, NN - 1);
    const int gbrow = min(row0 + rb, NN - 1);
    const size_t gA1 = (size_t)garow * 256 + oa;
    const size_t gA2 = (size_t)gbrow * 256 + ob;
    const size_t gB1 = (size_t)(c0 + ra) * 256 + oa;
    const size_t gB2 = (size_t)(c0 + rb) * 256 + ob;

    for (int kk = 0; kk < 256; kk += 32) {
        __syncthreads();
        gl_lds16(A + gA1 + kk, &As[ca * 8]);
        gl_lds16(A + gA2 + kk, &As[cb * 8]);
        gl_lds16(BT + gB1 + kk, &Bs[ca * 8]);
        gl_lds16(BT + gB2 + kk, &Bs[cb * 8]);
        __syncthreads();

        frag_ab a[4], b[4];
#pragma unroll
        for (int mt = 0; mt < 4; ++mt)
            a[mt] = *(const frag_ab*)&As[(wm * 64 + mt * 16 + l16) * 32 + quad * 8];
#pragma unroll
        for (int nt = 0; nt < 4; ++nt)
            b[nt] = *(const frag_ab*)&Bs[(wn * 64 + nt * 16 + l16) * 32 + quad * 8];
#pragma unroll
        for (int mt = 0; mt < 4; ++mt)
#pragma unroll
            for (int nt = 0; nt < 4; ++nt)
                acc[mt][nt] = __builtin_amdgcn_mfma_f32_16x16x32_bf16(
                    a[mt], b[nt], acc[mt][nt], 0, 0, 0);
    }

#pragma unroll
    for (int nt = 0; nt < 4; ++nt) {
        int col = c0 + wn * 64 + nt * 16 + l16;
        float bv = bias[col];
#pragma unroll
        for (int mt = 0; mt < 4; ++mt) {
#pragma unroll
            for (int r = 0; r < 4; ++r) {
                int row = row0 + wm * 64 + mt * 16 + quad * 4 + r;
                if (row < NN) {
                    float v = acc[mt][nt][r] + bv;
                    if (relu) v = fmaxf(v, 0.f);
                    C[(size_t)row * ldc + coloff + col] = f2b(v);
                }
            }
        }
    }
}

// ---------------- fused GEMM2+GEMM3: t3o3 = (relu(A@BT2^T+br2)) @ BT3^T + bias3 ----
// Stage 1: full 128x256 h2 tile into XOR-swizzled LDS (bf16, same rounding as
// the unfused path). Stage 2: GEMM3 with A straight from LDS (no staging).
// Swizzle idx^=((row&7)<<3) breaks the 512B-stride 16-way bank conflict on the
// stage-2 ds_read_b128 (lanes l16 read 16 rows at one col) down to 2-way (free).
// LDS = 8+8+64 = 80 KB -> 2 blocks/CU.

__global__ __launch_bounds__(256, 2) void gemm23_kernel(
    const u16* __restrict__ A, const u16* __restrict__ BT2,
    const float* __restrict__ br2, const u16* __restrict__ BT3,
    const float* __restrict__ bias3, u16* __restrict__ C) {
    __shared__ alignas(16) u16 As[128 * 32];
    __shared__ alignas(16) u16 Bs[128 * 32];
    __shared__ alignas(16) u16 Hs[128 * 256];
    const int t = threadIdx.x;
    const int lane = t & 63, wid = t >> 6;
    const int quad = lane >> 4, l16 = lane & 15;
    const int wm = wid >> 1, wn = wid & 1;
    const int row0 = blockIdx.x * 128;

    const int ca = t, cb = t + 256;
    const int ra = ca >> 2, oa = (ca & 3) * 8;
    const int rb = cb >> 2, ob = (cb & 3) * 8;
    const int garow = min(row0 + ra, NN - 1);
    const int gbrow = min(row0 + rb, NN - 1);
    const size_t gA1 = (size_t)garow * 256 + oa;
    const size_t gA2 = (size_t)gbrow * 256 + ob;

    // ---- stage 1: h2 tile (both 128-col halves) ----
    for (int nb = 0; nb < 2; ++nb) {
        const int c0 = nb * 128;
        frag_cd acc[4][4];
#pragma unroll
        for (int i = 0; i < 4; ++i)
#pragma unroll
            for (int j = 0; j < 4; ++j) acc[i][j] = (frag_cd)0.f;

        for (int kk = 0; kk < 256; kk += 32) {
            __syncthreads();
            gl_lds16(A + gA1 + kk, &As[ca * 8]);
            gl_lds16(A + gA2 + kk, &As[cb * 8]);
            gl_lds16(BT2 + (size_t)(c0 + ra) * 256 + kk + oa, &Bs[ca * 8]);
            gl_lds16(BT2 + (size_t)(c0 + rb) * 256 + kk + ob, &Bs[cb * 8]);
            __syncthreads();

            frag_ab a[4], b[4];
#pragma unroll
            for (int mt = 0; mt < 4; ++mt)
                a[mt] = *(const frag_ab*)&As[(wm * 64 + mt * 16 + l16) * 32 + quad * 8];
#pragma unroll
            for (int nt = 0; nt < 4; ++nt)
                b[nt] = *(const frag_ab*)&Bs[(wn * 64 + nt * 16 + l16) * 32 + quad * 8];
#pragma unroll
            for (int mt = 0; mt < 4; ++mt)
#pragma unroll
                for (int nt = 0; nt < 4; ++nt)
                    acc[mt][nt] = __builtin_amdgcn_mfma_f32_16x16x32_bf16(
                        a[mt], b[nt], acc[mt][nt], 0, 0, 0);
        }
        // park h2 half-tile in LDS (bias + relu + bf16 round)
#pragma unroll
        for (int nt = 0; nt < 4; ++nt) {
            int col = c0 + wn * 64 + nt * 16 + l16;
            float bv = br2[col];
#pragma unroll
            for (int mt = 0; mt < 4; ++mt) {
#pragma unroll
                for (int r = 0; r < 4; ++r) {
                    int lr = wm * 64 + mt * 16 + quad * 4 + r;
                    float v = fmaxf(acc[mt][nt][r] + bv, 0.f);
                    Hs[(lr * 256 + col) ^ ((lr & 7) << 3)] = f2b(v);
                }
            }
        }
    }
    __syncthreads();

    // ---- stage 2: C = Hs @ BT3^T + bias3 (A from LDS, no staging) ----
    for (int nb = 0; nb < 2; ++nb) {
        const int c0 = nb * 128;
        frag_cd acc[4][4];
#pragma unroll
        for (int i = 0; i < 4; ++i)
#pragma unroll
            for (int j = 0; j < 4; ++j) acc[i][j] = (frag_cd)0.f;

        for (int kk = 0; kk < 256; kk += 32) {
            __syncthreads();
            gl_lds16(BT3 + (size_t)(c0 + ra) * 256 + kk + oa, &Bs[ca * 8]);
            gl_lds16(BT3 + (size_t)(c0 + rb) * 256 + kk + ob, &Bs[cb * 8]);
            __syncthreads();

            frag_ab a[4], b[4];
#pragma unroll
            for (int mt = 0; mt < 4; ++mt) {
                int lr = wm * 64 + mt * 16 + l16;
                a[mt] = *(const frag_ab*)&Hs[(lr * 256 + kk + quad * 8) ^ ((lr & 7) << 3)];
            }
#pragma unroll
            for (int nt = 0; nt < 4; ++nt)
                b[nt] = *(const frag_ab*)&Bs[(wn * 64 + nt * 16 + l16) * 32 + quad * 8];
#pragma unroll
            for (int mt = 0; mt < 4; ++mt)
#pragma unroll
                for (int nt = 0; nt < 4; ++nt)
                    acc[mt][nt] = __builtin_amdgcn_mfma_f32_16x16x32_bf16(
                        a[mt], b[nt], acc[mt][nt], 0, 0, 0);
        }
#pragma unroll
        for (int nt = 0; nt < 4; ++nt) {
            int col = c0 + wn * 64 + nt * 16 + l16;
            float bv = bias3[col];
#pragma unroll
            for (int mt = 0; mt < 4; ++mt) {
#pragma unroll
                for (int r = 0; r < 4; ++r) {
                    int row = row0 + wm * 64 + mt * 16 + quad * 4 + r;
                    if (row < NN) {
                        float v = acc[mt][nt][r] + bv;
                        C[(size_t)row * 256 + col] = f2b(v);
                    }
                }
            }
        }
    }
}

// ---------------- fused pull3 + mean-pool + head (per-graph, 16 waves) -----------
// pooled_agg[g] = sum over the graph's contiguous CSR edge range of t3[src]
// (per-node aggregation is unnecessary -- pool is a sum over nodes).
// Per 64-edge group: one u16 load puts 64 src indices in a register; __shfl
// (LDS counter) feeds gather addresses -> batch k+1's 4 gathers issue while
// batch k accumulates = 8 gathers in flight on a clean vmcnt stream.

__device__ inline int lower_bound_i(const int* a, int n, int v) {
    int lo = 0, hi = n;
    while (lo < hi) {
        int m = (lo + hi) >> 1;
        if (a[m] < v) lo = m + 1; else hi = m;
    }
    return lo;
}

__global__ __launch_bounds__(1024) void pool3_kernel(
    const u32* __restrict__ Tu, const int* __restrict__ ofs,
    const u16* __restrict__ srcl, const int* __restrict__ batch,
    const float* __restrict__ W1, const float* __restrict__ b1,
    const float* __restrict__ W2, const float* __restrict__ b2,
    float* __restrict__ out) {
    __shared__ float red[16][128];
    __shared__ float po[8][128];
    __shared__ float p[128];
    __shared__ float hid[40];
    int g = blockIdx.x, t = threadIdx.x;
    int w = t >> 6, lane = t & 63;
    int q = lane >> 4, l = lane & 15;
    int n_lo = lower_bound_i(batch, NN, g);
    int n_hi = lower_bound_i(batch, NN, g + 1);
    int glo = ofs[n_lo], ghi = ofs[n_hi];   // ofs[NN] == EE

    float2 a0 = {0.f, 0.f}, a1 = {0.f, 0.f}, a2 = {0.f, 0.f}, a3 = {0.f, 0.f};
    for (int gb = glo + w * 64; gb < ghi; gb += 1024) {
        int nedge = ghi - gb;
        if (nedge > 64) nedge = 64;
        int idx = (lane < nedge) ? (int)srcl[gb + lane] : 0;
        if (nedge == 64) {
            int s0 = __shfl(idx, q, 64);
            int s1 = __shfl(idx, 4 + q, 64);
            int s2 = __shfl(idx, 8 + q, 64);
            int s3 = __shfl(idx, 12 + q, 64);
            uint4 v0 = *(const uint4*)(Tu + (size_t)s0 * 128 + l * 4);
            uint4 v1 = *(const uint4*)(Tu + (size_t)s1 * 128 + l * 4);
            uint4 v2 = *(const uint4*)(Tu + (size_t)s2 * 128 + l * 4);
            uint4 v3 = *(const uint4*)(Tu + (size_t)s3 * 128 + l * 4);
#pragma unroll
            for (int b = 1; b < 4; ++b) {
                int u0 = __shfl(idx, b * 16 + q, 64);
                int u1 = __shfl(idx, b * 16 + 4 + q, 64);
                int u2 = __shfl(idx, b * 16 + 8 + q, 64);
                int u3 = __shfl(idx, b * 16 + 12 + q, 64);
                uint4 w0 = *(const uint4*)(Tu + (size_t)u0 * 128 + l * 4);
                uint4 w1 = *(const uint4*)(Tu + (size_t)u1 * 128 + l * 4);
                uint4 w2 = *(const uint4*)(Tu + (size_t)u2 * 128 + l * 4);
                uint4 w3 = *(const uint4*)(Tu + (size_t)u3 * 128 + l * 4);
                acc2(a0, v0.x); acc2(a1, v0.y); acc2(a2, v0.z); acc2(a3, v0.w);
                acc2(a0, v1.x); acc2(a1, v1.y); acc2(a2, v1.z); acc2(a3, v1.w);
                acc2(a0, v2.x); acc2(a1, v2.y); acc2(a2, v2.z); acc2(a3, v2.w);
                acc2(a0, v3.x); acc2(a1, v3.y); acc2(a2, v3.z); acc2(a3, v3.w);
                v0 = w0; v1 = w1; v2 = w2; v3 = w3;
            }
            acc2(a0, v0.x); acc2(a1, v0.y); acc2(a2, v0.z); acc2(a3, v0.w);
            acc2(a0, v1.x); acc2(a1, v1.y); acc2(a2, v1.z); acc2(a3, v1.w);
            acc2(a0, v2.x); acc2(a1, v2.y); acc2(a2, v2.z); acc2(a3, v2.w);
            acc2(a0, v3.x); acc2(a1, v3.y); acc2(a2, v3.z); acc2(a3, v3.w);
        } else {
#pragma unroll
            for (int b = 0; b < 4; ++b) {
#pragma unroll
                for (int sl = 0; sl < 4; ++sl) {
                    int e = b * 16 + sl * 4 + q;
                    int s = __shfl(idx, e, 64);
                    if (e < nedge) {
                        uint4 v = *(const uint4*)(Tu + (size_t)s * 128 + l * 4);
                        acc2(a0, v.x); acc2(a1, v.y); acc2(a2, v.z); acc2(a3, v.w);
                    }
                }
            }
        }
    }
    float acc[8] = {a0.x, a0.y, a1.x, a1.y, a2.x, a2.y, a3.x, a3.y};
#pragma unroll
    for (int i = 0; i < 8; ++i) {
        acc[i] += __shfl_xor(acc[i], 16, 64);
        acc[i] += __shfl_xor(acc[i], 32, 64);
    }
    if (q == 0) {
#pragma unroll
        for (int i = 0; i < 8; ++i) red[w][l * 8 + i] = acc[i];
    }
    // o3 per-graph row sum: ch = t&127, row group t>>7 (stride 8)
    float so = 0.f;
    int ch = t & 127, rg = t >> 7;
    for (int r = n_lo + rg; r < n_hi; r += 8)
        so += b2f(Tu[(size_t)r * 128 + 64 + (ch >> 1)], ch & 1);
    po[rg][ch] = so;
    __syncthreads();
    if (t < 128) {
        float s = 0.f;
#pragma unroll
        for (int k = 0; k < 16; ++k) s += red[k][t];
#pragma unroll
        for (int k = 0; k < 8; ++k) s += po[k][t];
        p[t] = s / fmaxf((float)(n_hi - n_lo), 1.f);
    }
    __syncthreads();
    if (t < 40) {
        float v = b1[t];
        for (int k = 0; k < 128; ++k) v += p[k] * W1[k * 40 + t];
        hid[t] = v;
    }
    __syncthreads();
    if (t < 10) {
        float v = b2[t];
        for (int j = 0; j < 40; ++j) v += hid[j] * W2[j * 10 + t];
        out[g * 10 + t] = v;
    }
}

// ---------------- launch ----------------

extern "C" void kernel_launch(void* const* d_in, const int* in_sizes, int n_in,
                              void* d_out, int out_size, void* d_ws, size_t ws_size,
                              hipStream_t stream) {
    const float* x   = (const float*)d_in[0];
    const int* ei    = (const int*)d_in[1];
    const int* batch = (const int*)d_in[2];
    const float* Wr1 = (const float*)d_in[3];
    const float* br1 = (const float*)d_in[4];
    const float* Wo1 = (const float*)d_in[5];
    const float* Wr2 = (const float*)d_in[6];
    const float* br2 = (const float*)d_in[7];
    const float* Wo2 = (const float*)d_in[8];
    const float* Wr3 = (const float*)d_in[9];
    const float* br3 = (const float*)d_in[10];
    const float* Wo3 = (const float*)d_in[11];
    const float* W1  = (const float*)d_in[12];
    const float* b1  = (const float*)d_in[13];
    const float* W2  = (const float*)d_in[14];
    const float* b2  = (const float*)d_in[15];
    float* out = (float*)d_out;

    char* ws = (char*)d_ws;
    size_t off = 0;
    auto alloc = [&](size_t bytes) {
        void* p = ws + off;
        off += (bytes + 255) & ~(size_t)255;
        return p;
    };
    int* ofs      = (int*)alloc((NN + 1) * sizeof(int));
    int* bcnt     = (int*)alloc(256 * sizeof(int));
    u16* srcl     = (u16*)alloc((size_t)EE * 2);
    u16* ax       = (u16*)alloc((size_t)NN * 256 * 2);   // cols 0-127 agg, 128-255 x_bf
    u16* ah1      = (u16*)alloc((size_t)NN * 256 * 2);   // cols 0-127 agg(h1), 128-255 h1
    u16* t3o3     = (u16*)alloc((size_t)NN * 256 * 2);   // cols 0-127 t3, 128-255 o3
    u16* BT1      = (u16*)alloc(128 * 256 * 2);
    u16* BT2      = (u16*)alloc(256 * 256 * 2);
    u16* BT3      = (u16*)alloc(256 * 256 * 2);
    float* bias3  = (float*)alloc(256 * sizeof(float));
    // pairs (12.85 MB) overlays t3o3 (25.6 MB): pairs lifetime ends at bfill,
    // t3o3 first written at gemm23.
    u32* pairs = (u32*)t3o3;

    hipMemsetAsync(bcnt, 0, 256 * sizeof(int), stream);

    // CSR pass 1 + x->bf16 + weight prep (fused, independent block ranges)
    bscatter_prep_kernel<<<SCBLKS + XBLKS + 256, 256, 0, stream>>>(
        ei, bcnt, pairs, x, ax, Wr1, Wo1, Wr2, Wo2, Wr3, Wo3, br3,
        BT1, BT2, BT3, bias3);
    // CSR pass 2
    bfill_kernel<<<NB, 512, 0, stream>>>(pairs, bcnt, ofs, srcl);

    // conv1
    pull_bf_kernel<<<NN * 64 / 256, 256, 0, stream>>>((const u32*)ax + 64, ofs, srcl, (u32*)ax);
    gemm_bf_kernel<<<dim3(1, 391), 256, 0, stream>>>(ax, BT1, br1, ah1, 256, 128, 1);
    // conv2
    pull_bf_kernel<<<NN * 64 / 256, 256, 0, stream>>>((const u32*)ah1 + 64, ofs, srcl, (u32*)ah1);
    // conv2 GEMM + conv3 GEMM fused: t3o3 = relu(ah1@BT2^T+br2) @ BT3^T + bias3
    gemm23_kernel<<<391, 256, 0, stream>>>(ah1, BT2, br2, BT3, bias3, t3o3);

    // fused: h3-aggregation + mean pool + head (per graph, flat CSR edge range)
    pool3_kernel<<<GG, 1024, 0, stream>>>((const u32*)t3o3, ofs, srcl, batch,
                                          W1, b1, W2, b2, out);
}

// Round 5
// 344.166 us; speedup vs baseline: 1.3740x; 1.0230x over previous
//
#include <hip/hip_runtime.h>
#include <hip/hip_bf16.h>
#include <cstddef>

#define NN 50000
#define EE 1600000
#define GG 512
#define NB 196        // ceil(NN/256) buckets of 256 nodes
#define BSTRIDE 16384 // fixed pairs-region capacity per bucket (max span ~8600)
#define BCAP 10240    // LDS staging per bucket
#define XBLKS 6250    // NN*32/256 x-convert blocks
#define SCBLKS 782    // ceil(EE/2048) bscatter blocks
#define PSEG 8        // edge segments per graph in pool3_seg

typedef unsigned int u32;
typedef unsigned short u16;
typedef __attribute__((ext_vector_type(8))) short frag_ab;   // 8 bf16 = 4 VGPRs
typedef __attribute__((ext_vector_type(4))) float frag_cd;   // 4 fp32 acc

__device__ __forceinline__ void gl_lds16(const void* g, void* l) {
    __builtin_amdgcn_global_load_lds(
        (const __attribute__((address_space(1))) u32*)g,
        (__attribute__((address_space(3))) u32*)l, 16, 0, 0);
}
__device__ __forceinline__ float b2f_lo(u32 v) { return __uint_as_float(v << 16); }
__device__ __forceinline__ float b2f_hi(u32 v) { return __uint_as_float(v & 0xffff0000u); }
__device__ __forceinline__ float b2f(u32 v, int odd) { return odd ? b2f_hi(v) : b2f_lo(v); }
__device__ __forceinline__ u16 f2b(float x) {
    __hip_bfloat16 h = __float2bfloat16(x);
    return *(u16*)&h;
}
__device__ __forceinline__ u32 pack2(float lo, float hi) {
    return ((u32)f2b(hi) << 16) | f2b(lo);
}
__device__ __forceinline__ void acc2(float2& a, u32 v) {
    a.x += b2f_lo(v);
    a.y += b2f_hi(v);
}

__device__ inline int lower_bound_i(const int* a, int n, int v) {
    int lo = 0, hi = n;
    while (lo < hi) {
        int m = (lo + hi) >> 1;
        if (a[m] < v) lo = m + 1; else hi = m;
    }
    return lo;
}

// Gather rate is queue-depth-bound: needs pull-class occupancy (many 256-thread
// blocks, 4 loads in flight per lane). pool3 is split: pool3_seg (G x 8 segment
// blocks, pull_bf-shaped inner loop, deterministic psum partials, o3 folded in)
// + tiny per-graph head kernel.

// ---------------- fused: edge bucket-scatter + x->bf16 + weight prep + gn ----------

__global__ __launch_bounds__(256) void bscatter_prep_kernel(
    const int* __restrict__ ei, int* __restrict__ bcnt, u32* __restrict__ pairs,
    const float* __restrict__ x, u16* __restrict__ ax,
    const float* __restrict__ Wr1, const float* __restrict__ Wo1,
    const float* __restrict__ Wr2, const float* __restrict__ Wo2,
    const float* __restrict__ Wr3, const float* __restrict__ Wo3,
    const float* __restrict__ br3,
    u16* __restrict__ BT1, u16* __restrict__ BT2, u16* __restrict__ BT3,
    float* __restrict__ bias3, const int* __restrict__ batch,
    int* __restrict__ gn) {
    __shared__ int lcnt[NB];
    __shared__ int lbase[NB];
    __shared__ unsigned short lpos[2048];
    int bid = blockIdx.x, t = threadIdx.x;
    if (bid < SCBLKS) {
        int e0 = bid * 2048;
        u32 pk[8];   // packed (src<<8)|(dst&255) stashed across phases
        int bk[8];
        for (int i = t; i < NB; i += 256) lcnt[i] = 0;
        __syncthreads();
#pragma unroll
        for (int i = 0; i < 8; ++i) {
            int e = e0 + i * 256 + t;
            if (e < EE) {
                int dst = ei[EE + e], src = ei[e];
                int b = dst >> 8;
                bk[i] = b;
                pk[i] = ((u32)src << 8) | (u32)(dst & 255);
                lpos[i * 256 + t] = (unsigned short)atomicAdd(&lcnt[b], 1);
            } else bk[i] = -1;
        }
        __syncthreads();
        for (int i = t; i < NB; i += 256) lbase[i] = atomicAdd(&bcnt[i], lcnt[i]);
        __syncthreads();
#pragma unroll
        for (int i = 0; i < 8; ++i) {
            if (bk[i] >= 0) {
                int pos = lbase[bk[i]] + (int)lpos[i * 256 + t];
                pairs[(size_t)bk[i] * BSTRIDE + pos] = pk[i];
            }
        }
    } else if (bid < SCBLKS + XBLKS) {
        int idx = (bid - SCBLKS) * 256 + t;
        int row = idx >> 5, q = idx & 31;
        float4 v = *(const float4*)(x + (size_t)row * 128 + q * 4);
        *(u32*)(ax + (size_t)row * 256 + 128 + q * 4) = pack2(v.x, v.y);
        *(u32*)(ax + (size_t)row * 256 + 128 + q * 4 + 2) = pack2(v.z, v.w);
    } else if (bid < SCBLKS + XBLKS + 256) {
        int m = bid - SCBLKS - XBLKS;   // 0..255 output col
        int k = t;                       // reduction idx
        BT2[m * 256 + k] = f2b(k < 128 ? Wr2[k * 256 + m] : Wo2[(k - 128) * 256 + m]);
        BT3[m * 256 + k] = f2b(m < 128 ? Wr3[k * 128 + m] : Wo3[k * 128 + (m - 128)]);
        if (m < 128)
            BT1[m * 256 + k] = f2b(k < 128 ? Wr1[k * 128 + m] : Wo1[(k - 128) * 128 + m]);
        if (k == 0) bias3[m] = (m < 128) ? 0.f : br3[m - 128];
    } else {
        int g = (bid - SCBLKS - XBLKS - 256) * 256 + t;   // 0..767
        if (g <= GG) gn[g] = lower_bound_i(batch, NN, g);
    }
}

// ---------------- CSR pass 2 (512 threads/block; srcl in u16) ----------------

__global__ __launch_bounds__(512) void bfill_kernel(const u32* __restrict__ pairs,
                                                    const int* __restrict__ bcnt,
                                                    int* __restrict__ ofs,
                                                    u16* __restrict__ srcl) {
    __shared__ int sc[256];
    __shared__ int cnts[256];
    __shared__ int lcnt[256];
    __shared__ int lcur[256];
    __shared__ int lbuf[BCAP];
    int b = blockIdx.x, t = threadIdx.x;
    if (t < 256) {
        int c = (t < NB) ? bcnt[t] : 0;
        cnts[t] = c;
        sc[t] = c;
        lcnt[t] = 0;
    }
    __syncthreads();
    for (int off = 1; off < 256; off <<= 1) {
        int v = (t >= off && t < 256) ? sc[t - off] : 0;
        __syncthreads();
        if (t < 256) sc[t] += v;
        __syncthreads();
    }
    int base = sc[b] - cnts[b];
    int span = cnts[b];
    const u32* pp = pairs + (size_t)b * BSTRIDE;
    for (int j = t; j < span; j += 512) atomicAdd(&lcnt[pp[j] & 255u], 1);
    __syncthreads();
    int nc = 0;
    if (t < 256) {
        nc = lcnt[t];
        sc[t] = nc;
    }
    __syncthreads();
    for (int off = 1; off < 256; off <<= 1) {
        int v = (t >= off && t < 256) ? sc[t - off] : 0;
        __syncthreads();
        if (t < 256) sc[t] += v;
        __syncthreads();
    }
    if (t < 256) {
        int excl = sc[t] - nc;
        int node = b * 256 + t;
        if (node < NN) ofs[node] = base + excl;
        lcur[t] = excl;
    }
    if (b == 0 && t == 256) ofs[NN] = EE;
    __syncthreads();
    for (int j = t; j < span; j += 512) {
        u32 p = pp[j];
        int pos = atomicAdd(&lcur[p & 255u], 1);
        int src = (int)(p >> 8);
        if (pos < BCAP) lbuf[pos] = src;
        else srcl[base + pos] = (u16)src;
    }
    __syncthreads();
    int lim = span < BCAP ? span : BCAP;
    for (int j = t; j < lim; j += 512) srcl[base + j] = (u16)lbuf[j];
}

// ---------------- bf16 pull, row-major, wide-load, 16-edge unroll (R0 proven) ----

__global__ __launch_bounds__(256) void pull_bf_kernel(const u32* __restrict__ Xu,
                                                      const int* __restrict__ ofs,
                                                      const u16* __restrict__ srcl,
                                                      u32* __restrict__ outu) {
    int node = (blockIdx.x * 256 + threadIdx.x) >> 6;
    int lane = threadIdx.x & 63;
    int q = lane >> 4, l = lane & 15;
    int lo = ofs[node], hi = ofs[node + 1];
    float2 a0 = {0.f, 0.f}, a1 = {0.f, 0.f}, a2 = {0.f, 0.f}, a3 = {0.f, 0.f};
    int j = lo;
    for (; j + 15 < hi; j += 16) {
        int s0 = srcl[j + q], s1 = srcl[j + 4 + q];
        int s2 = srcl[j + 8 + q], s3 = srcl[j + 12 + q];
        uint4 v0 = *(const uint4*)(Xu + (size_t)s0 * 128 + l * 4);
        uint4 v1 = *(const uint4*)(Xu + (size_t)s1 * 128 + l * 4);
        uint4 v2 = *(const uint4*)(Xu + (size_t)s2 * 128 + l * 4);
        uint4 v3 = *(const uint4*)(Xu + (size_t)s3 * 128 + l * 4);
        acc2(a0, v0.x); acc2(a1, v0.y); acc2(a2, v0.z); acc2(a3, v0.w);
        acc2(a0, v1.x); acc2(a1, v1.y); acc2(a2, v1.z); acc2(a3, v1.w);
        acc2(a0, v2.x); acc2(a1, v2.y); acc2(a2, v2.z); acc2(a3, v2.w);
        acc2(a0, v3.x); acc2(a1, v3.y); acc2(a2, v3.z); acc2(a3, v3.w);
    }
    for (; j + 3 < hi; j += 4) {
        int s = srcl[j + q];
        uint4 v = *(const uint4*)(Xu + (size_t)s * 128 + l * 4);
        acc2(a0, v.x); acc2(a1, v.y); acc2(a2, v.z); acc2(a3, v.w);
    }
    if (j + q < hi) {
        int s = srcl[j + q];
        uint4 v = *(const uint4*)(Xu + (size_t)s * 128 + l * 4);
        acc2(a0, v.x); acc2(a1, v.y); acc2(a2, v.z); acc2(a3, v.w);
    }
    float acc[8] = {a0.x, a0.y, a1.x, a1.y, a2.x, a2.y, a3.x, a3.y};
#pragma unroll
    for (int i = 0; i < 8; ++i) {
        acc[i] += __shfl_xor(acc[i], 16, 64);
        acc[i] += __shfl_xor(acc[i], 32, 64);
    }
    if (q == 0) {
        uint4 r;
        r.x = pack2(acc[0], acc[1]);
        r.y = pack2(acc[2], acc[3]);
        r.z = pack2(acc[4], acc[5]);
        r.w = pack2(acc[6], acc[7]);
        *(uint4*)(outu + (size_t)node * 128 + l * 4) = r;
    }
}

// ---------------- bf16 MFMA GEMM: C = relu?(A @ BT^T + bias), K=256 ----------------

__global__ __launch_bounds__(256, 2) void gemm_bf_kernel(
    const u16* __restrict__ A, const u16* __restrict__ BT,
    const float* __restrict__ bias, u16* __restrict__ C,
    int ldc, int coloff, int relu) {
    __shared__ alignas(16) u16 As[128 * 32];
    __shared__ alignas(16) u16 Bs[128 * 32];
    const int t = threadIdx.x;
    const int lane = t & 63, wid = t >> 6;
    const int quad = lane >> 4, l16 = lane & 15;
    const int wm = wid >> 1, wn = wid & 1;
    const int row0 = blockIdx.y * 128, c0 = blockIdx.x * 128;

    frag_cd acc[4][4];
#pragma unroll
    for (int i = 0; i < 4; ++i)
#pragma unroll
        for (int j = 0; j < 4; ++j) acc[i][j] = (frag_cd)0.f;

    const int ca = t, cb = t + 256;
    const int ra = ca >> 2, oa = (ca & 3) * 8;
    const int rb = cb >> 2, ob = (cb & 3) * 8;
    const int garow = min(row0 + ra, NN - 1);
    const int gbrow = min(row0 + rb, NN - 1);
    const size_t gA1 = (size_t)garow * 256 + oa;
    const size_t gA2 = (size_t)gbrow * 256 + ob;
    const size_t gB1 = (size_t)(c0 + ra) * 256 + oa;
    const size_t gB2 = (size_t)(c0 + rb) * 256 + ob;

    for (int kk = 0; kk < 256; kk += 32) {
        __syncthreads();
        gl_lds16(A + gA1 + kk, &As[ca * 8]);
        gl_lds16(A + gA2 + kk, &As[cb * 8]);
        gl_lds16(BT + gB1 + kk, &Bs[ca * 8]);
        gl_lds16(BT + gB2 + kk, &Bs[cb * 8]);
        __syncthreads();

        frag_ab a[4], b[4];
#pragma unroll
        for (int mt = 0; mt < 4; ++mt)
            a[mt] = *(const frag_ab*)&As[(wm * 64 + mt * 16 + l16) * 32 + quad * 8];
#pragma unroll
        for (int nt = 0; nt < 4; ++nt)
            b[nt] = *(const frag_ab*)&Bs[(wn * 64 + nt * 16 + l16) * 32 + quad * 8];
#pragma unroll
        for (int mt = 0; mt < 4; ++mt)
#pragma unroll
            for (int nt = 0; nt < 4; ++nt)
                acc[mt][nt] = __builtin_amdgcn_mfma_f32_16x16x32_bf16(
                    a[mt], b[nt], acc[mt][nt], 0, 0, 0);
    }

#pragma unroll
    for (int nt = 0; nt < 4; ++nt) {
        int col = c0 + wn * 64 + nt * 16 + l16;
        float bv = bias[col];
#pragma unroll
        for (int mt = 0; mt < 4; ++mt) {
#pragma unroll
            for (int r = 0; r < 4; ++r) {
                int row = row0 + wm * 64 + mt * 16 + quad * 4 + r;
                if (row < NN) {
                    float v = acc[mt][nt][r] + bv;
                    if (relu) v = fmaxf(v, 0.f);
                    C[(size_t)row * ldc + coloff + col] = f2b(v);
                }
            }
        }
    }
}

// ---------------- fused GEMM2+GEMM3: t3o3 = (relu(A@BT2^T+br2)) @ BT3^T + bias3 ----

__global__ __launch_bounds__(256, 2) void gemm23_kernel(
    const u16* __restrict__ A, const u16* __restrict__ BT2,
    const float* __restrict__ br2, const u16* __restrict__ BT3,
    const float* __restrict__ bias3, u16* __restrict__ C) {
    __shared__ alignas(16) u16 As[128 * 32];
    __shared__ alignas(16) u16 Bs[128 * 32];
    __shared__ alignas(16) u16 Hs[128 * 256];
    const int t = threadIdx.x;
    const int lane = t & 63, wid = t >> 6;
    const int quad = lane >> 4, l16 = lane & 15;
    const int wm = wid >> 1, wn = wid & 1;
    const int row0 = blockIdx.x * 128;

    const int ca = t, cb = t + 256;
    const int ra = ca >> 2, oa = (ca & 3) * 8;
    const int rb = cb >> 2, ob = (cb & 3) * 8;
    const int garow = min(row0 + ra, NN - 1);
    const int gbrow = min(row0 + rb, NN - 1);
    const size_t gA1 = (size_t)garow * 256 + oa;
    const size_t gA2 = (size_t)gbrow * 256 + ob;

    // ---- stage 1: h2 tile (both 128-col halves) ----
    for (int nb = 0; nb < 2; ++nb) {
        const int c0 = nb * 128;
        frag_cd acc[4][4];
#pragma unroll
        for (int i = 0; i < 4; ++i)
#pragma unroll
            for (int j = 0; j < 4; ++j) acc[i][j] = (frag_cd)0.f;

        for (int kk = 0; kk < 256; kk += 32) {
            __syncthreads();
            gl_lds16(A + gA1 + kk, &As[ca * 8]);
            gl_lds16(A + gA2 + kk, &As[cb * 8]);
            gl_lds16(BT2 + (size_t)(c0 + ra) * 256 + kk + oa, &Bs[ca * 8]);
            gl_lds16(BT2 + (size_t)(c0 + rb) * 256 + kk + ob, &Bs[cb * 8]);
            __syncthreads();

            frag_ab a[4], b[4];
#pragma unroll
            for (int mt = 0; mt < 4; ++mt)
                a[mt] = *(const frag_ab*)&As[(wm * 64 + mt * 16 + l16) * 32 + quad * 8];
#pragma unroll
            for (int nt = 0; nt < 4; ++nt)
                b[nt] = *(const frag_ab*)&Bs[(wn * 64 + nt * 16 + l16) * 32 + quad * 8];
#pragma unroll
            for (int mt = 0; mt < 4; ++mt)
#pragma unroll
                for (int nt = 0; nt < 4; ++nt)
                    acc[mt][nt] = __builtin_amdgcn_mfma_f32_16x16x32_bf16(
                        a[mt], b[nt], acc[mt][nt], 0, 0, 0);
        }
        // park h2 half-tile in LDS (bias + relu + bf16 round)
#pragma unroll
        for (int nt = 0; nt < 4; ++nt) {
            int col = c0 + wn * 64 + nt * 16 + l16;
            float bv = br2[col];
#pragma unroll
            for (int mt = 0; mt < 4; ++mt) {
#pragma unroll
                for (int r = 0; r < 4; ++r) {
                    int lr = wm * 64 + mt * 16 + quad * 4 + r;
                    float v = fmaxf(acc[mt][nt][r] + bv, 0.f);
                    Hs[(lr * 256 + col) ^ ((lr & 7) << 3)] = f2b(v);
                }
            }
        }
    }
    __syncthreads();

    // ---- stage 2: C = Hs @ BT3^T + bias3 (A from LDS, no staging) ----
    for (int nb = 0; nb < 2; ++nb) {
        const int c0 = nb * 128;
        frag_cd acc[4][4];
#pragma unroll
        for (int i = 0; i < 4; ++i)
#pragma unroll
            for (int j = 0; j < 4; ++j) acc[i][j] = (frag_cd)0.f;

        for (int kk = 0; kk < 256; kk += 32) {
            __syncthreads();
            gl_lds16(BT3 + (size_t)(c0 + ra) * 256 + kk + oa, &Bs[ca * 8]);
            gl_lds16(BT3 + (size_t)(c0 + rb) * 256 + kk + ob, &Bs[cb * 8]);
            __syncthreads();

            frag_ab a[4], b[4];
#pragma unroll
            for (int mt = 0; mt < 4; ++mt) {
                int lr = wm * 64 + mt * 16 + l16;
                a[mt] = *(const frag_ab*)&Hs[(lr * 256 + kk + quad * 8) ^ ((lr & 7) << 3)];
            }
#pragma unroll
            for (int nt = 0; nt < 4; ++nt)
                b[nt] = *(const frag_ab*)&Bs[(wn * 64 + nt * 16 + l16) * 32 + quad * 8];
#pragma unroll
            for (int mt = 0; mt < 4; ++mt)
#pragma unroll
                for (int nt = 0; nt < 4; ++nt)
                    acc[mt][nt] = __builtin_amdgcn_mfma_f32_16x16x32_bf16(
                        a[mt], b[nt], acc[mt][nt], 0, 0, 0);
        }
#pragma unroll
        for (int nt = 0; nt < 4; ++nt) {
            int col = c0 + wn * 64 + nt * 16 + l16;
            float bv = bias3[col];
#pragma unroll
            for (int mt = 0; mt < 4; ++mt) {
#pragma unroll
                for (int r = 0; r < 4; ++r) {
                    int row = row0 + wm * 64 + mt * 16 + quad * 4 + r;
                    if (row < NN) {
                        float v = acc[mt][nt][r] + bv;
                        C[(size_t)row * 256 + col] = f2b(v);
                    }
                }
            }
        }
    }
}

// ---------------- pool3_seg: per-(graph,segment) gather partials ------------------
// Grid GG*PSEG x 256 threads (4 waves). Each wave: contiguous edge sub-range,
// verbatim pull_bf inner loop (4 gathers in flight). o3 row partial folded in.
// Deterministic psum[g][seg][128] f32 output, no atomics.

__global__ __launch_bounds__(256) void pool3_seg_kernel(
    const u32* __restrict__ Tu, const int* __restrict__ ofs,
    const u16* __restrict__ srcl, const int* __restrict__ gn,
    float* __restrict__ psum) {
    __shared__ float red[4][128];
    __shared__ float po[2][128];
    int gb = blockIdx.x;
    int g = gb >> 3, s = gb & 7;
    int t = threadIdx.x;
    int w = t >> 6, lane = t & 63;
    int q = lane >> 4, l = lane & 15;
    int n_lo = gn[g], n_hi = gn[g + 1];
    int glo = ofs[n_lo], ghi = ofs[n_hi];
    int len = ghi - glo;
    int s_lo = glo + (int)(((long long)len * s) >> 3);
    int s_hi = glo + (int)(((long long)len * (s + 1)) >> 3);
    int slen = s_hi - s_lo;
    int wlo = s_lo + ((slen * w) >> 2);
    int whi = s_lo + ((slen * (w + 1)) >> 2);

    float2 a0 = {0.f, 0.f}, a1 = {0.f, 0.f}, a2 = {0.f, 0.f}, a3 = {0.f, 0.f};
    int j = wlo;
    for (; j + 15 < whi; j += 16) {
        int s0 = srcl[j + q], s1 = srcl[j + 4 + q];
        int s2 = srcl[j + 8 + q], s3 = srcl[j + 12 + q];
        uint4 v0 = *(const uint4*)(Tu + (size_t)s0 * 128 + l * 4);
        uint4 v1 = *(const uint4*)(Tu + (size_t)s1 * 128 + l * 4);
        uint4 v2 = *(const uint4*)(Tu + (size_t)s2 * 128 + l * 4);
        uint4 v3 = *(const uint4*)(Tu + (size_t)s3 * 128 + l * 4);
        acc2(a0, v0.x); acc2(a1, v0.y); acc2(a2, v0.z); acc2(a3, v0.w);
        acc2(a0, v1.x); acc2(a1, v1.y); acc2(a2, v1.z); acc2(a3, v1.w);
        acc2(a0, v2.x); acc2(a1, v2.y); acc2(a2, v2.z); acc2(a3, v2.w);
        acc2(a0, v3.x); acc2(a1, v3.y); acc2(a2, v3.z); acc2(a3, v3.w);
    }
    for (; j + 3 < whi; j += 4) {
        int sv = srcl[j + q];
        uint4 v = *(const uint4*)(Tu + (size_t)sv * 128 + l * 4);
        acc2(a0, v.x); acc2(a1, v.y); acc2(a2, v.z); acc2(a3, v.w);
    }
    if (j + q < whi) {
        int sv = srcl[j + q];
        uint4 v = *(const uint4*)(Tu + (size_t)sv * 128 + l * 4);
        acc2(a0, v.x); acc2(a1, v.y); acc2(a2, v.z); acc2(a3, v.w);
    }
    float acc[8] = {a0.x, a0.y, a1.x, a1.y, a2.x, a2.y, a3.x, a3.y};
#pragma unroll
    for (int i = 0; i < 8; ++i) {
        acc[i] += __shfl_xor(acc[i], 16, 64);
        acc[i] += __shfl_xor(acc[i], 32, 64);
    }
    if (q == 0) {
#pragma unroll
        for (int i = 0; i < 8; ++i) red[w][l * 8 + i] = acc[i];
    }
    // o3 partial: 16 row streams (8 segs x 2 rowgroups), rows step 16
    float so = 0.f;
    int ch = t & 127, rg = t >> 7;
    for (int r = n_lo + s * 2 + rg; r < n_hi; r += 16)
        so += b2f(Tu[(size_t)r * 128 + 64 + (ch >> 1)], ch & 1);
    po[rg][ch] = so;
    __syncthreads();
    if (t < 128) {
        float v = red[0][t] + red[1][t] + red[2][t] + red[3][t] + po[0][t] + po[1][t];
        psum[((size_t)g * PSEG + s) * 128 + t] = v;
    }
}

// ---------------- per-graph head: reduce 8 partials, mean, MLP ---------------------

__global__ __launch_bounds__(128) void head_kernel(
    const float* __restrict__ psum, const int* __restrict__ gn,
    const float* __restrict__ W1, const float* __restrict__ b1,
    const float* __restrict__ W2, const float* __restrict__ b2,
    float* __restrict__ out) {
    __shared__ float p[128];
    __shared__ float hid[40];
    int g = blockIdx.x, t = threadIdx.x;
    int cnt = gn[g + 1] - gn[g];
    float sv = 0.f;
#pragma unroll
    for (int k = 0; k < PSEG; ++k) sv += psum[((size_t)g * PSEG + k) * 128 + t];
    p[t] = sv / fmaxf((float)cnt, 1.f);
    __syncthreads();
    if (t < 40) {
        float v = b1[t];
        for (int k = 0; k < 128; ++k) v += p[k] * W1[k * 40 + t];
        hid[t] = v;
    }
    __syncthreads();
    if (t < 10) {
        float v = b2[t];
        for (int j = 0; j < 40; ++j) v += hid[j] * W2[j * 10 + t];
        out[g * 10 + t] = v;
    }
}

// ---------------- launch ----------------

extern "C" void kernel_launch(void* const* d_in, const int* in_sizes, int n_in,
                              void* d_out, int out_size, void* d_ws, size_t ws_size,
                              hipStream_t stream) {
    const float* x   = (const float*)d_in[0];
    const int* ei    = (const int*)d_in[1];
    const int* batch = (const int*)d_in[2];
    const float* Wr1 = (const float*)d_in[3];
    const float* br1 = (const float*)d_in[4];
    const float* Wo1 = (const float*)d_in[5];
    const float* Wr2 = (const float*)d_in[6];
    const float* br2 = (const float*)d_in[7];
    const float* Wo2 = (const float*)d_in[8];
    const float* Wr3 = (const float*)d_in[9];
    const float* br3 = (const float*)d_in[10];
    const float* Wo3 = (const float*)d_in[11];
    const float* W1  = (const float*)d_in[12];
    const float* b1  = (const float*)d_in[13];
    const float* W2  = (const float*)d_in[14];
    const float* b2  = (const float*)d_in[15];
    float* out = (float*)d_out;

    char* ws = (char*)d_ws;
    size_t off = 0;
    auto alloc = [&](size_t bytes) {
        void* p = ws + off;
        off += (bytes + 255) & ~(size_t)255;
        return p;
    };
    int* ofs      = (int*)alloc((NN + 1) * sizeof(int));
    int* bcnt     = (int*)alloc(256 * sizeof(int));
    int* gn       = (int*)alloc((GG + 1) * sizeof(int));
    u16* srcl     = (u16*)alloc((size_t)EE * 2);
    u16* ax       = (u16*)alloc((size_t)NN * 256 * 2);   // cols 0-127 agg, 128-255 x_bf
    u16* ah1      = (u16*)alloc((size_t)NN * 256 * 2);   // cols 0-127 agg(h1), 128-255 h1
    u16* t3o3     = (u16*)alloc((size_t)NN * 256 * 2);   // cols 0-127 t3, 128-255 o3
    float* psum   = (float*)alloc((size_t)GG * PSEG * 128 * sizeof(float));
    u16* BT1      = (u16*)alloc(128 * 256 * 2);
    u16* BT2      = (u16*)alloc(256 * 256 * 2);
    u16* BT3      = (u16*)alloc(256 * 256 * 2);
    float* bias3  = (float*)alloc(256 * sizeof(float));
    // pairs (12.85 MB) overlays t3o3 (25.6 MB): pairs lifetime ends at bfill,
    // t3o3 first written at gemm23.
    u32* pairs = (u32*)t3o3;

    hipMemsetAsync(bcnt, 0, 256 * sizeof(int), stream);

    // CSR pass 1 + x->bf16 + weight prep + graph node-ranges (fused ranges)
    bscatter_prep_kernel<<<SCBLKS + XBLKS + 256 + 3, 256, 0, stream>>>(
        ei, bcnt, pairs, x, ax, Wr1, Wo1, Wr2, Wo2, Wr3, Wo3, br3,
        BT1, BT2, BT3, bias3, batch, gn);
    // CSR pass 2
    bfill_kernel<<<NB, 512, 0, stream>>>(pairs, bcnt, ofs, srcl);

    // conv1
    pull_bf_kernel<<<NN * 64 / 256, 256, 0, stream>>>((const u32*)ax + 64, ofs, srcl, (u32*)ax);
    gemm_bf_kernel<<<dim3(1, 391), 256, 0, stream>>>(ax, BT1, br1, ah1, 256, 128, 1);
    // conv2
    pull_bf_kernel<<<NN * 64 / 256, 256, 0, stream>>>((const u32*)ah1 + 64, ofs, srcl, (u32*)ah1);
    // conv2 GEMM + conv3 GEMM fused: t3o3 = relu(ah1@BT2^T+br2) @ BT3^T + bias3
    gemm23_kernel<<<391, 256, 0, stream>>>(ah1, BT2, br2, BT3, bias3, t3o3);

    // fused h3-aggregation + pool partials (per graph-segment), then head
    pool3_seg_kernel<<<GG * PSEG, 256, 0, stream>>>((const u32*)t3o3, ofs, srcl, gn, psum);
    head_kernel<<<GG, 128, 0, stream>>>(psum, gn, W1, b1, W2, b2, out);
}